// Round 17
// baseline (354.855 us; speedup 1.0000x reference)
//
#include <hip/hip_runtime.h>
#include <hip/hip_bf16.h>
#include <math.h>

constexpr int N_NODES = 80000;
constexpr int N_EDGES = 480000;
constexpr int N_B     = 800;
constexpr int PADDEG  = 64;     // padded CSR row (Poisson(6): P(deg>=64) ~ 1e-42)

typedef __attribute__((ext_vector_type(8))) short bf16x8;
typedef __attribute__((ext_vector_type(4))) float f32x4;

__device__ __forceinline__ float gelu_exact(float x) {
    return 0.5f * x * (1.0f + erff(x * 0.70710678118654752f));
}
__device__ __forceinline__ float lrelu(float v) {
    return v > 0.f ? v : 0.2f * v;
}
// fp32 <-> bf16 (RNE)
__device__ __forceinline__ unsigned short f2bf(float f) {
    unsigned u = __float_as_uint(f);
    unsigned r = u + 0x7FFFu + ((u >> 16) & 1u);
    return (unsigned short)(r >> 16);
}
__device__ __forceinline__ float bf2f(unsigned short h) {
    return __uint_as_float(((unsigned)h) << 16);
}

// ---------------- GAT node transform: MFMA bf16, D = W·X^T --------------------------
// Operands swapped vs naive: A=W(ch rows), B=x(node cols) -> D col=node, row=ch.
// Lane then owns 4 CONSECUTIVE channels of ONE node: ushort4 stores, 2-step s/d reduce.
template<int IN_DIM>
__launch_bounds__(256, 2)
__global__ void gat_transform(const float* __restrict__ xin,
                              const float* __restrict__ W,    // [256, IN_DIM] row-major
                              const float* __restrict__ aS,   // [256]
                              const float* __restrict__ aD,
                              unsigned short* __restrict__ hfull,  // [N,256] bf16
                              float* __restrict__ sArr,       // [N,4]
                              float* __restrict__ dArr) {
    constexpr int K  = (IN_DIM + 31) & ~31;     // 32 or 64
    constexpr int KS = K / 32;                  // k-steps
    constexpr int KP = K + 8;                   // +8 bf16 row pad
    __shared__ __align__(16) unsigned short Wb[256 * KP];
    __shared__ __align__(16) unsigned short xs[32 * KP];

    const int tid = threadIdx.x;
    const int lane = tid & 63, w = tid >> 6;

    for (int idx = tid; idx < 256 * K; idx += 256) {
        int c = idx / K, k = idx - c * K;
        Wb[c * KP + k] = (k < IN_DIM) ? f2bf(W[c * IN_DIM + k]) : (unsigned short)0;
    }
    __syncthreads();

    // W fragments (A operand): lane holds W[ch = w*64 + t*16 + (lane&15)][k]
    bf16x8 wfrag[4][KS];
    float4 as4[4], ad4[4];
#pragma unroll
    for (int t = 0; t < 4; ++t) {
        const int ch = w * 64 + t * 16 + (lane & 15);
#pragma unroll
        for (int s = 0; s < KS; ++s)
            wfrag[t][s] = *reinterpret_cast<const bf16x8*>(&Wb[ch * KP + s * 32 + (lane >> 4) * 8]);
        const int chb = w * 64 + t * 16 + (lane >> 4) * 4;   // channels this lane OUTPUTS
        as4[t] = *reinterpret_cast<const float4*>(&aS[chb]);
        ad4[t] = *reinterpret_cast<const float4*>(&aD[chb]);
    }

    const int ntiles = N_NODES / 32;
    for (int tile = blockIdx.x; tile < ntiles; tile += gridDim.x) {
        const int n0 = tile * 32;
        __syncthreads();
        for (int idx = tid; idx < 32 * K; idx += 256) {
            int r = idx / K, k = idx - r * K;
            xs[r * KP + k] = (k < IN_DIM) ? f2bf(xin[(size_t)(n0 + r) * IN_DIM + k])
                                          : (unsigned short)0;
        }
        __syncthreads();

#pragma unroll
        for (int m = 0; m < 2; ++m) {
            // x fragment (B operand): lane holds x[node = m*16 + (lane&15)][k]
            bf16x8 xfrag[KS];
#pragma unroll
            for (int s = 0; s < KS; ++s)
                xfrag[s] = *reinterpret_cast<const bf16x8*>(
                    &xs[(m * 16 + (lane & 15)) * KP + s * 32 + (lane >> 4) * 8]);

            const int node = n0 + m * 16 + (lane & 15);
            float sv = 0.f, dv = 0.f;
#pragma unroll
            for (int t = 0; t < 4; ++t) {
                f32x4 a = {0.f, 0.f, 0.f, 0.f};
#pragma unroll
                for (int s = 0; s < KS; ++s)
                    a = __builtin_amdgcn_mfma_f32_16x16x32_bf16(wfrag[t][s], xfrag[s], a, 0, 0, 0);
                // D row = ch = w*64 + t*16 + (lane>>4)*4 + j, col = node (lane&15)
                ushort4 hb;
                hb.x = f2bf(a[0]); hb.y = f2bf(a[1]); hb.z = f2bf(a[2]); hb.w = f2bf(a[3]);
                const int chb = w * 64 + t * 16 + (lane >> 4) * 4;
                *reinterpret_cast<ushort4*>(&hfull[(size_t)node * 256 + chb]) = hb;
                sv += a[0] * as4[t].x + a[1] * as4[t].y + a[2] * as4[t].z + a[3] * as4[t].w;
                dv += a[0] * ad4[t].x + a[1] * ad4[t].y + a[2] * ad4[t].z + a[3] * ad4[t].w;
            }
            sv += __shfl_xor(sv, 16, 64); dv += __shfl_xor(dv, 16, 64);
            sv += __shfl_xor(sv, 32, 64); dv += __shfl_xor(dv, 32, 64);
            if (lane < 16) {
                sArr[node * 4 + w] = sv;
                dArr[node * 4 + w] = dv;
            }
        }
    }
}

// ---------------- padded CSR build (once per call) ----------------------------------
__global__ void csr_scatter_pad(const int* __restrict__ ei,
                                int* __restrict__ cnt, int* __restrict__ csrc) {
    int e = blockIdx.x * 256 + threadIdx.x;
    if (e >= N_EDGES) return;
    int src = ei[e], dst = ei[N_EDGES + e];
    int slot = atomicAdd(&cnt[dst], 1);
    csrc[(size_t)dst * PADDEG + slot] = src;
}

// ---------------- fused alpha + gather: FOUR dst nodes per wave, 4-deep MLP ---------
// qbuf transposed [head][slot]: phase-2 reads q for 4 edges as one float4.
template<bool POOL>
__launch_bounds__(256)
__global__ void gat_gather(const int* __restrict__ cnt, const int* __restrict__ csrc,
                           const float* __restrict__ sArr, const float* __restrict__ dArr,
                           const unsigned short* __restrict__ hfull, // [N,256] bf16
                           const float* __restrict__ bias,
                           const float* __restrict__ poolW, const float* __restrict__ poolB,
                           float* __restrict__ xout,
                           float* __restrict__ logit, float* __restrict__ pmax) {
    constexpr int CAP = PADDEG;
    __shared__ float qbuf[4][4][4 * CAP];   // [wid][nl][h*CAP + s]
    __shared__ int   sbuf[4][4][CAP];
    __shared__ float red[16];

    const int wid = threadIdx.x >> 6;
    const int lane = threadIdx.x & 63;
    const int nl = lane >> 4;            // node within wave (0..3)
    const int sub = lane & 15;
    const int n = blockIdx.x * 16 + wid * 4 + nl;

    const int jb = n * PADDEG;
    const int deg = cnt[n];

    // ---- phase 1: q = exp(lrelu(s+d)), Z accumulate ----
    const int hh = sub & 3;
    const int slot = sub >> 2;           // 0..3
    const float dv = dArr[n * 4 + hh];
    const float qself = expf(lrelu(sArr[n * 4 + hh] + dv));
    float zp = 0.f;

    for (int base = 0; base < deg; base += 4) {
        int s = base + slot;
        if (s < deg) {
            int src = csrc[jb + s];
            float q = expf(lrelu(sArr[src * 4 + hh] + dv));
            qbuf[wid][nl][hh * CAP + s] = q;
            if (hh == 0) sbuf[wid][nl][s] = src;
            zp += q;
        }
    }
    zp += __shfl_xor(zp, 4, 64);
    zp += __shfl_xor(zp, 8, 64);
    const float inv = 0.25f / (zp + qself);
    __threadfence_block();

    // ---- phase 2: gather, 16 channels/lane, 4-deep MLP ----
    const int h = sub >> 2;              // head of this lane's channels
    const int c16 = sub * 16;
    const int bl = (lane & 48) + h;      // lane in same node with hh==h, slot==0
    const float inv_g = __shfl(inv, bl, 64);
    const float qs_g  = __shfl(qself, bl, 64);

#define LOADU4(S, C) (*reinterpret_cast<const uint4*>(&hfull[(size_t)(unsigned)(S) * 256 + (C)]))
#define UNPK8(A, B, Q, U) { \
    A[B + 0] = fmaf((Q), __uint_as_float((U).x << 16),          A[B + 0]); \
    A[B + 1] = fmaf((Q), __uint_as_float((U).x & 0xFFFF0000u),  A[B + 1]); \
    A[B + 2] = fmaf((Q), __uint_as_float((U).y << 16),          A[B + 2]); \
    A[B + 3] = fmaf((Q), __uint_as_float((U).y & 0xFFFF0000u),  A[B + 3]); \
    A[B + 4] = fmaf((Q), __uint_as_float((U).z << 16),          A[B + 4]); \
    A[B + 5] = fmaf((Q), __uint_as_float((U).z & 0xFFFF0000u),  A[B + 5]); \
    A[B + 6] = fmaf((Q), __uint_as_float((U).w << 16),          A[B + 6]); \
    A[B + 7] = fmaf((Q), __uint_as_float((U).w & 0xFFFF0000u),  A[B + 7]); }

    float acc[16] = {0, 0, 0, 0, 0, 0, 0, 0, 0, 0, 0, 0, 0, 0, 0, 0};
    {
        uint4 ua = LOADU4(n, c16);
        uint4 ub = LOADU4(n, c16 + 8);
        UNPK8(acc, 0, qs_g, ua);
        UNPK8(acc, 8, qs_g, ub);
    }
    int s = 0;
    for (; s + 3 < deg; s += 4) {
        int4  s4 = *reinterpret_cast<const int4*>(&sbuf[wid][nl][s]);          // 16B aligned
        float4 q4 = *reinterpret_cast<const float4*>(&qbuf[wid][nl][h * CAP + s]);
        uint4 u0a = LOADU4(s4.x, c16); uint4 u0b = LOADU4(s4.x, c16 + 8);
        uint4 u1a = LOADU4(s4.y, c16); uint4 u1b = LOADU4(s4.y, c16 + 8);
        uint4 u2a = LOADU4(s4.z, c16); uint4 u2b = LOADU4(s4.z, c16 + 8);
        uint4 u3a = LOADU4(s4.w, c16); uint4 u3b = LOADU4(s4.w, c16 + 8);
        UNPK8(acc, 0, q4.x, u0a); UNPK8(acc, 8, q4.x, u0b);
        UNPK8(acc, 0, q4.y, u1a); UNPK8(acc, 8, q4.y, u1b);
        UNPK8(acc, 0, q4.z, u2a); UNPK8(acc, 8, q4.z, u2b);
        UNPK8(acc, 0, q4.w, u3a); UNPK8(acc, 8, q4.w, u3b);
    }
    for (; s + 1 < deg; s += 2) {
        int s0 = sbuf[wid][nl][s], s1 = sbuf[wid][nl][s + 1];
        float q0 = qbuf[wid][nl][h * CAP + s];
        float q1 = qbuf[wid][nl][h * CAP + s + 1];
        uint4 u0a = LOADU4(s0, c16);
        uint4 u0b = LOADU4(s0, c16 + 8);
        uint4 u1a = LOADU4(s1, c16);
        uint4 u1b = LOADU4(s1, c16 + 8);
        UNPK8(acc, 0, q0, u0a);
        UNPK8(acc, 8, q0, u0b);
        UNPK8(acc, 0, q1, u1a);
        UNPK8(acc, 8, q1, u1b);
    }
    if (s < deg) {
        int s0 = sbuf[wid][nl][s];
        float q0 = qbuf[wid][nl][h * CAP + s];
        uint4 u0a = LOADU4(s0, c16);
        uint4 u0b = LOADU4(s0, c16 + 8);
        UNPK8(acc, 0, q0, u0a);
        UNPK8(acc, 8, q0, u0b);
    }
#undef UNPK8
#undef LOADU4

    // normalize by this head's 1/Z, then head-mean across the 4 head groups (bits 2,3)
#pragma unroll
    for (int j = 0; j < 16; ++j) acc[j] *= inv_g;
#pragma unroll
    for (int j = 0; j < 16; ++j) {
        acc[j] += __shfl_xor(acc[j], 4, 64);
        acc[j] += __shfl_xor(acc[j], 8, 64);
    }

    // lane (h, q=sub&3) finishes 4 contiguous channels cc = q*16 + h*4
    const int qq = sub & 3;
    const int cc = qq * 16 + h * 4;
    float v0 = (h == 0) ? acc[0] : (h == 1) ? acc[4] : (h == 2) ? acc[8]  : acc[12];
    float v1 = (h == 0) ? acc[1] : (h == 1) ? acc[5] : (h == 2) ? acc[9]  : acc[13];
    float v2 = (h == 0) ? acc[2] : (h == 1) ? acc[6] : (h == 2) ? acc[10] : acc[14];
    float v3 = (h == 0) ? acc[3] : (h == 1) ? acc[7] : (h == 2) ? acc[11] : acc[15];
    const float4 b4 = *reinterpret_cast<const float4*>(&bias[cc]);
    float4 o4;
    o4.x = gelu_exact(v0 + b4.x);
    o4.y = gelu_exact(v1 + b4.y);
    o4.z = gelu_exact(v2 + b4.z);
    o4.w = gelu_exact(v3 + b4.w);
    *reinterpret_cast<float4*>(&xout[(size_t)n * 64 + cc]) = o4;

    if (POOL) {
        const float4 pw = *reinterpret_cast<const float4*>(&poolW[cc]);
        float p = o4.x * pw.x + o4.y * pw.y + o4.z * pw.z + o4.w * pw.w;
#pragma unroll
        for (int of = 1; of < 16; of <<= 1) p += __shfl_xor(p, of, 64);
        float lg = p + poolB[0];
        if (sub == 0) {
            logit[n] = lg;
            red[wid * 4 + nl] = lg;
        }
        __syncthreads();
        if (threadIdx.x == 0) {
            float mm = red[0];
#pragma unroll
            for (int i = 1; i < 16; ++i) mm = fmaxf(mm, red[i]);
            pmax[blockIdx.x] = mm;
        }
    }
}

// ---------------- single-block global max -------------------------------------------
__global__ void reduce_max(const float* __restrict__ pmax, int n,
                           float* __restrict__ gmax) {
    __shared__ float red[256];
    float m = -INFINITY;
    for (int i = threadIdx.x; i < n; i += 256) m = fmaxf(m, pmax[i]);
    red[threadIdx.x] = m;
    __syncthreads();
    for (int s = 128; s > 0; s >>= 1) {
        if (threadIdx.x < s) red[threadIdx.x] = fmaxf(red[threadIdx.x], red[threadIdx.x + s]);
        __syncthreads();
    }
    if (threadIdx.x == 0) *gmax = red[0];
}

// ---------------- segment boundaries from sorted batch_idx ---------------------------
__global__ void seg_bounds(const int* __restrict__ batch, int* __restrict__ start) {
    int n = blockIdx.x * 256 + threadIdx.x;
    if (n >= N_NODES) return;
    int b1 = batch[n];
    int b0 = (n == 0) ? -1 : batch[n - 1];
    for (int b = b0 + 1; b <= b1; ++b) start[b] = n;
    if (n == N_NODES - 1)
        for (int b = b1 + 1; b <= N_B; ++b) start[b] = N_NODES;
}

// ---------------- per-graph pooling ---------------------------------------------------
__global__ void pool_graph(const float* __restrict__ h3,
                           const float* __restrict__ logit,
                           const float* __restrict__ gmax,
                           const int* __restrict__ start,
                           float* __restrict__ pooled,
                           float* __restrict__ gsum) {
    __shared__ float sacc[4][64];
    __shared__ float sw[4];
    int b = blockIdx.x;
    int s = start[b], e = start[b + 1];
    int lane = threadIdx.x & 63, wid = threadIdx.x >> 6;
    float M = *gmax;
    float acc = 0.f, wsum = 0.f;
    for (int n = s + wid; n < e; n += 4) {
        float w = expf(logit[n] - M);
        acc += h3[(size_t)n * 64 + lane] * w;
        if (lane == 0) wsum += w;
    }
    sacc[wid][lane] = acc;
    if (lane == 0) sw[wid] = wsum;
    __syncthreads();
    if (wid == 0) {
        pooled[(size_t)b * 64 + lane] = sacc[0][lane] + sacc[1][lane] + sacc[2][lane] + sacc[3][lane];
        if (lane == 0) atomicAdd(gsum, sw[0] + sw[1] + sw[2] + sw[3]);
    }
}

// ---------------- head1 split-K part: 8 graphs/block --------------------------------
constexpr int GB1  = 8;
constexpr int KSEG = 372;   // 744 = 2 segments of 372 (93 aligned float4)

__launch_bounds__(256, 4)
__global__ void head1_part(const float* __restrict__ pooled, const float* __restrict__ gsum,
                           const float* __restrict__ rnafm, const float* __restrict__ hand,
                           const float* __restrict__ e1W,
                           float* __restrict__ part) {   // [2][N_B][256]
    __shared__ __align__(16) float fused[GB1][KSEG + 4];
    const int bq = blockIdx.x >> 1;
    const int ks = blockIdx.x & 1;
    const int g0 = bq * GB1;
    const int k0 = ks * KSEG;
    const int tid = threadIdx.x;
    const float inv = 1.0f / *gsum;

    for (int idx = tid; idx < GB1 * KSEG; idx += 256) {
        int g = idx / KSEG, kk = idx - g * KSEG;
        int k = kk + k0;
        int b = g0 + g;
        float v;
        if (k < 64)       v = pooled[(size_t)b * 64 + k] * inv;
        else if (k < 704) v = rnafm[(size_t)b * 640 + (k - 64)];
        else              v = hand[(size_t)b * 40 + (k - 704)];
        fused[g][kk] = v;
    }
    __syncthreads();

    const float* wr = e1W + (size_t)tid * 744 + k0;
    float a0 = 0.f, a1 = 0.f, a2 = 0.f, a3 = 0.f;
    float a4 = 0.f, a5 = 0.f, a6 = 0.f, a7 = 0.f;
    for (int q = 0; q < KSEG / 4; ++q) {
        float4 w4 = *reinterpret_cast<const float4*>(wr + q * 4);
        float4 f0 = *reinterpret_cast<const float4*>(&fused[0][q * 4]);
        float4 f1 = *reinterpret_cast<const float4*>(&fused[1][q * 4]);
        float4 f2 = *reinterpret_cast<const float4*>(&fused[2][q * 4]);
        float4 f3 = *reinterpret_cast<const float4*>(&fused[3][q * 4]);
        float4 f4 = *reinterpret_cast<const float4*>(&fused[4][q * 4]);
        float4 f5 = *reinterpret_cast<const float4*>(&fused[5][q * 4]);
        float4 f6 = *reinterpret_cast<const float4*>(&fused[6][q * 4]);
        float4 f7 = *reinterpret_cast<const float4*>(&fused[7][q * 4]);
        a0 += f0.x * w4.x + f0.y * w4.y + f0.z * w4.z + f0.w * w4.w;
        a1 += f1.x * w4.x + f1.y * w4.y + f1.z * w4.z + f1.w * w4.w;
        a2 += f2.x * w4.x + f2.y * w4.y + f2.z * w4.z + f2.w * w4.w;
        a3 += f3.x * w4.x + f3.y * w4.y + f3.z * w4.z + f3.w * w4.w;
        a4 += f4.x * w4.x + f4.y * w4.y + f4.z * w4.z + f4.w * w4.w;
        a5 += f5.x * w4.x + f5.y * w4.y + f5.z * w4.z + f5.w * w4.w;
        a6 += f6.x * w4.x + f6.y * w4.y + f6.z * w4.z + f6.w * w4.w;
        a7 += f7.x * w4.x + f7.y * w4.y + f7.z * w4.z + f7.w * w4.w;
    }
    float* po = part + ((size_t)ks * N_B + g0) * 256 + tid;
    po[0 * 256] = a0; po[1 * 256] = a1; po[2 * 256] = a2; po[3 * 256] = a3;
    po[4 * 256] = a4; po[5 * 256] = a5; po[6 * 256] = a6; po[7 * 256] = a7;
}

// ---------------- fused head tail: LN + e2 + {binary, per, cls}, 4 graphs/block ------
__launch_bounds__(256, 2)
__global__ void head_fused(const float* __restrict__ part,
                           const float* __restrict__ e1b,
                           const float* __restrict__ lng, const float* __restrict__ lnb,
                           const float* __restrict__ e2W, const float* __restrict__ e2b,
                           const float* __restrict__ binW, const float* __restrict__ binB,
                           const float* __restrict__ ad1W, const float* __restrict__ ad1b,
                           const float* __restrict__ ad2W, const float* __restrict__ ad2b,
                           const float* __restrict__ c1W, const float* __restrict__ c1b,
                           const float* __restrict__ c2W, const float* __restrict__ c2b,
                           float* __restrict__ out) {
    __shared__ float zr[4][256];
    __shared__ float red1[4][4], red2[4][4];
    __shared__ float sv[4][128];
    __shared__ float t64[4][64];
    __shared__ float h1s[4][5][32];
    __shared__ float binred[4][32];
    const int b0 = blockIdx.x * 4;
    const int tid = threadIdx.x;
    const int lane = tid & 63, wid = tid >> 6;

    // --- stage 1: z1 = LN(gelu(partA+partB+bias)) for 4 graphs, tid = channel ---
    const float eb = e1b[tid];
    float g0 = gelu_exact(part[(size_t)(b0 + 0) * 256 + tid] + part[((size_t)N_B + b0 + 0) * 256 + tid] + eb);
    float g1 = gelu_exact(part[(size_t)(b0 + 1) * 256 + tid] + part[((size_t)N_B + b0 + 1) * 256 + tid] + eb);
    float g2 = gelu_exact(part[(size_t)(b0 + 2) * 256 + tid] + part[((size_t)N_B + b0 + 2) * 256 + tid] + eb);
    float g3 = gelu_exact(part[(size_t)(b0 + 3) * 256 + tid] + part[((size_t)N_B + b0 + 3) * 256 + tid] + eb);

    float s10 = g0, s11 = g1, s12 = g2, s13 = g3;
    float s20 = g0 * g0, s21 = g1 * g1, s22 = g2 * g2, s23 = g3 * g3;
#pragma unroll
    for (int o = 1; o < 64; o <<= 1) {
        s10 += __shfl_xor(s10, o, 64); s11 += __shfl_xor(s11, o, 64);
        s12 += __shfl_xor(s12, o, 64); s13 += __shfl_xor(s13, o, 64);
        s20 += __shfl_xor(s20, o, 64); s21 += __shfl_xor(s21, o, 64);
        s22 += __shfl_xor(s22, o, 64); s23 += __shfl_xor(s23, o, 64);
    }
    if (lane == 0) {
        red1[wid][0] = s10; red1[wid][1] = s11; red1[wid][2] = s12; red1[wid][3] = s13;
        red2[wid][0] = s20; red2[wid][1] = s21; red2[wid][2] = s22; red2[wid][3] = s23;
    }
    __syncthreads();

    const float gN = lng[tid], bN = lnb[tid];
#pragma unroll
    for (int bb = 0; bb < 4; ++bb) {
        float s1 = red1[0][bb] + red1[1][bb] + red1[2][bb] + red1[3][bb];
        float s2 = red2[0][bb] + red2[1][bb] + red2[2][bb] + red2[3][bb];
        float mu  = s1 * (1.0f / 256.0f);
        float var = s2 * (1.0f / 256.0f) - mu * mu;
        float g = (bb == 0) ? g0 : (bb == 1) ? g1 : (bb == 2) ? g2 : g3;
        zr[bb][tid] = (g - mu) * rsqrtf(var + 1e-5f) * gN + bN;
    }
    __syncthreads();

    // --- stage 2: shr = gelu(z1 @ e2W^T + e2b); tid -> (ch = tid&127, gp = tid>>7) ---
    {
        const int ch = tid & 127, gp = tid >> 7;   // gp covers graphs gp*2, gp*2+1
        const float* wr = e2W + (size_t)ch * 256;
        const float e2bb = e2b[ch];
        float a0 = e2bb, a1 = e2bb;
        for (int k = 0; k < 256; k += 4) {
            float4 w4 = *reinterpret_cast<const float4*>(wr + k);
            float4 f0 = *reinterpret_cast<const float4*>(&zr[gp * 2][k]);
            float4 f1 = *reinterpret_cast<const float4*>(&zr[gp * 2 + 1][k]);
            a0 += f0.x * w4.x + f0.y * w4.y + f0.z * w4.z + f0.w * w4.w;
            a1 += f1.x * w4.x + f1.y * w4.y + f1.z * w4.z + f1.w * w4.w;
        }
        sv[gp * 2][ch]     = gelu_exact(a0);
        sv[gp * 2 + 1][ch] = gelu_exact(a1);
    }
    __syncthreads();

    // --- stage 3: t64 (c1), h1s (ad1), binary partials ---
    for (int idx = tid; idx < 256 + 640; idx += 256) {
        if (idx < 256) {
            int g = idx >> 6, ch = idx & 63;
            float a = c1b[ch];
            const float* wr = c1W + (size_t)ch * 128;
            for (int k = 0; k < 128; ++k) a += sv[g][k] * wr[k];
            t64[g][ch] = gelu_exact(a);
        } else {
            int j = idx - 256;
            int g = j / 160, r = j - g * 160;
            int e = r >> 5, hh = r & 31;
            float a = ad1b[e * 32 + hh];
            const float* wr = ad1W + (size_t)(e * 32 + hh) * 128;
            for (int k = 0; k < 128; ++k) a += sv[g][k] * wr[k];
            h1s[g][e][hh] = gelu_exact(a);
        }
    }
    if (tid < 128) {
        int g = tid >> 5, r = tid & 31;
        float a = 0.f;
#pragma unroll
        for (int k = 0; k < 4; ++k) a += sv[g][r * 4 + k] * binW[r * 4 + k];
        binred[g][r] = a;
    }
    __syncthreads();

    // --- stage 4: finals ---
    if (tid < 24) {            // cls: 6 x 4 graphs
        int g = tid / 6, c = tid - g * 6;
        float a = c2b[c];
        const float* wr = c2W + (size_t)c * 64;
        for (int k = 0; k < 64; ++k) a += t64[g][k] * wr[k];
        out[4800 + (size_t)(b0 + g) * 6 + c] = a;
    }
    if (tid >= 32 && tid < 52) {  // per: 5 x 4 graphs
        int j = tid - 32;
        int g = j / 5, e = j - g * 5;
        float a = ad2b[e];
        const float* wr = ad2W + (size_t)e * 32;
        for (int k = 0; k < 32; ++k) a += h1s[g][e][k] * wr[k];
        out[800 + (size_t)e * 800 + (b0 + g)] = a;
    }
    if (tid >= 64 && tid < 68) {  // binary: 4 graphs
        int g = tid - 64;
        float a = binB[0];
        for (int r = 0; r < 32; ++r) a += binred[g][r];
        out[b0 + g] = a;
    }
}

extern "C" void kernel_launch(void* const* d_in, const int* in_sizes, int n_in,
                              void* d_out, int out_size, void* d_ws, size_t ws_size,
                              hipStream_t stream) {
    const float* x       = (const float*)d_in[0];
    const int*   ei      = (const int*)d_in[1];
    const int*   batch   = (const int*)d_in[2];
    const float* rnafm   = (const float*)d_in[3];
    const float* hand    = (const float*)d_in[4];
    const float* gW[3]  = {(const float*)d_in[5],  (const float*)d_in[9],  (const float*)d_in[13]};
    const float* gAs[3] = {(const float*)d_in[6],  (const float*)d_in[10], (const float*)d_in[14]};
    const float* gAd[3] = {(const float*)d_in[7],  (const float*)d_in[11], (const float*)d_in[15]};
    const float* gB[3]  = {(const float*)d_in[8],  (const float*)d_in[12], (const float*)d_in[16]};
    const float* poolW = (const float*)d_in[17];
    const float* poolB = (const float*)d_in[18];
    const float* e1W = (const float*)d_in[19]; const float* e1b = (const float*)d_in[20];
    const float* lng = (const float*)d_in[21]; const float* lnb = (const float*)d_in[22];
    const float* e2W = (const float*)d_in[23]; const float* e2b = (const float*)d_in[24];
    const float* binW = (const float*)d_in[25]; const float* binB = (const float*)d_in[26];
    const float* ad1W = (const float*)d_in[27]; const float* ad1b = (const float*)d_in[28];
    const float* ad2W = (const float*)d_in[29]; const float* ad2b = (const float*)d_in[30];
    const float* c1W = (const float*)d_in[31]; const float* c1b = (const float*)d_in[32];
    const float* c2W = (const float*)d_in[33]; const float* c2b = (const float*)d_in[34];
    float* out = (float*)d_out;

    float* ws = (float*)d_ws;
    size_t off = 0;
    unsigned short* hfull = (unsigned short*)(ws + off); off += (size_t)N_NODES * 128; // bf16 [N,256]
    float* xcur   = ws + off; off += (size_t)N_NODES * 64;
    float* sArr   = ws + off; off += (size_t)N_NODES * 4;
    float* dArr   = ws + off; off += (size_t)N_NODES * 4;
    int*   cnt    = (int*)(ws + off); off += N_NODES;
    int*   csrc   = (int*)(ws + off); off += (size_t)N_NODES * PADDEG;
    float* logit  = ws + off; off += N_NODES;
    float* pmax   = ws + off; off += 20000;
    float* pooled = ws + off; off += (size_t)N_B * 64;
    float* part   = ws + off; off += (size_t)2 * N_B * 256;
    int*   start  = (int*)(ws + off); off += (N_B + 1);
    float* gmax   = ws + off; off += 1;
    float* gsum   = ws + off; off += 1;

    // ---- one-time per call: padded CSR + segment bounds ----
    hipMemsetAsync(cnt, 0, N_NODES * sizeof(int), stream);
    csr_scatter_pad<<<(N_EDGES + 255) / 256, 256, 0, stream>>>(ei, cnt, csrc);
    seg_bounds<<<(N_NODES + 255) / 256, 256, 0, stream>>>(batch, start);

    // ---- 3 GAT layers ----
    for (int layer = 0; layer < 3; ++layer) {
        const float* xin = (layer == 0) ? x : xcur;
        if (layer == 0)
            gat_transform<21><<<512, 256, 0, stream>>>(xin, gW[0], gAs[0], gAd[0], hfull, sArr, dArr);
        else
            gat_transform<64><<<512, 256, 0, stream>>>(xin, gW[layer], gAs[layer], gAd[layer], hfull, sArr, dArr);
        if (layer < 2)
            gat_gather<false><<<N_NODES / 16, 256, 0, stream>>>(cnt, csrc, sArr, dArr, hfull,
                                                                gB[layer], nullptr, nullptr,
                                                                xcur, nullptr, nullptr);
        else
            gat_gather<true><<<N_NODES / 16, 256, 0, stream>>>(cnt, csrc, sArr, dArr, hfull,
                                                               gB[2], poolW, poolB,
                                                               xcur, logit, pmax);
    }

    // ---- pooling + heads ----
    reduce_max<<<1, 256, 0, stream>>>(pmax, N_NODES / 16, gmax);
    hipMemsetAsync(gsum, 0, sizeof(float), stream);
    pool_graph<<<N_B, 256, 0, stream>>>(xcur, logit, gmax, start, pooled, gsum);

    head1_part<<<(N_B / GB1) * 2, 256, 0, stream>>>(pooled, gsum, rnafm, hand, e1W, part);
    head_fused<<<N_B / 4, 256, 0, stream>>>(part, e1b, lng, lnb, e2W, e2b,
                                            binW, binB, ad1W, ad1b, ad2W, ad2b,
                                            c1W, c1b, c2W, c2b, out);
}

// Round 18
// 344.269 us; speedup vs baseline: 1.0307x; 1.0307x over previous
//
#include <hip/hip_runtime.h>
#include <hip/hip_bf16.h>
#include <math.h>

constexpr int N_NODES = 80000;
constexpr int N_EDGES = 480000;
constexpr int N_B     = 800;
constexpr int PADDEG  = 64;     // padded CSR row (Poisson(6): P(deg>=64) ~ 1e-42)
constexpr int NPMAX   = N_NODES / 16;   // 5000 pmax entries

typedef __attribute__((ext_vector_type(8))) short bf16x8;
typedef __attribute__((ext_vector_type(4))) float f32x4;

__device__ __forceinline__ float gelu_exact(float x) {
    return 0.5f * x * (1.0f + erff(x * 0.70710678118654752f));
}
__device__ __forceinline__ float lrelu(float v) {
    return v > 0.f ? v : 0.2f * v;
}
// fp32 <-> bf16 (RNE)
__device__ __forceinline__ unsigned short f2bf(float f) {
    unsigned u = __float_as_uint(f);
    unsigned r = u + 0x7FFFu + ((u >> 16) & 1u);
    return (unsigned short)(r >> 16);
}
__device__ __forceinline__ float bf2f(unsigned short h) {
    return __uint_as_float(((unsigned)h) << 16);
}

// ---------------- GAT node transform: MFMA bf16, D = W·X^T --------------------------
template<int IN_DIM>
__launch_bounds__(256, 2)
__global__ void gat_transform(const float* __restrict__ xin,
                              const float* __restrict__ W,    // [256, IN_DIM] row-major
                              const float* __restrict__ aS,   // [256]
                              const float* __restrict__ aD,
                              unsigned short* __restrict__ hfull,  // [N,256] bf16
                              float* __restrict__ sArr,       // [N,4]
                              float* __restrict__ dArr) {
    constexpr int K  = (IN_DIM + 31) & ~31;     // 32 or 64
    constexpr int KS = K / 32;                  // k-steps
    constexpr int KP = K + 8;                   // +8 bf16 row pad
    __shared__ __align__(16) unsigned short Wb[256 * KP];
    __shared__ __align__(16) unsigned short xs[32 * KP];

    const int tid = threadIdx.x;
    const int lane = tid & 63, w = tid >> 6;

    for (int idx = tid; idx < 256 * K; idx += 256) {
        int c = idx / K, k = idx - c * K;
        Wb[c * KP + k] = (k < IN_DIM) ? f2bf(W[c * IN_DIM + k]) : (unsigned short)0;
    }
    __syncthreads();

    bf16x8 wfrag[4][KS];
    float4 as4[4], ad4[4];
#pragma unroll
    for (int t = 0; t < 4; ++t) {
        const int ch = w * 64 + t * 16 + (lane & 15);
#pragma unroll
        for (int s = 0; s < KS; ++s)
            wfrag[t][s] = *reinterpret_cast<const bf16x8*>(&Wb[ch * KP + s * 32 + (lane >> 4) * 8]);
        const int chb = w * 64 + t * 16 + (lane >> 4) * 4;   // channels this lane OUTPUTS
        as4[t] = *reinterpret_cast<const float4*>(&aS[chb]);
        ad4[t] = *reinterpret_cast<const float4*>(&aD[chb]);
    }

    const int ntiles = N_NODES / 32;
    for (int tile = blockIdx.x; tile < ntiles; tile += gridDim.x) {
        const int n0 = tile * 32;
        __syncthreads();
        for (int idx = tid; idx < 32 * K; idx += 256) {
            int r = idx / K, k = idx - r * K;
            xs[r * KP + k] = (k < IN_DIM) ? f2bf(xin[(size_t)(n0 + r) * IN_DIM + k])
                                          : (unsigned short)0;
        }
        __syncthreads();

#pragma unroll
        for (int m = 0; m < 2; ++m) {
            bf16x8 xfrag[KS];
#pragma unroll
            for (int s = 0; s < KS; ++s)
                xfrag[s] = *reinterpret_cast<const bf16x8*>(
                    &xs[(m * 16 + (lane & 15)) * KP + s * 32 + (lane >> 4) * 8]);

            const int node = n0 + m * 16 + (lane & 15);
            float sv = 0.f, dv = 0.f;
#pragma unroll
            for (int t = 0; t < 4; ++t) {
                f32x4 a = {0.f, 0.f, 0.f, 0.f};
#pragma unroll
                for (int s = 0; s < KS; ++s)
                    a = __builtin_amdgcn_mfma_f32_16x16x32_bf16(wfrag[t][s], xfrag[s], a, 0, 0, 0);
                ushort4 hb;
                hb.x = f2bf(a[0]); hb.y = f2bf(a[1]); hb.z = f2bf(a[2]); hb.w = f2bf(a[3]);
                const int chb = w * 64 + t * 16 + (lane >> 4) * 4;
                *reinterpret_cast<ushort4*>(&hfull[(size_t)node * 256 + chb]) = hb;
                sv += a[0] * as4[t].x + a[1] * as4[t].y + a[2] * as4[t].z + a[3] * as4[t].w;
                dv += a[0] * ad4[t].x + a[1] * ad4[t].y + a[2] * ad4[t].z + a[3] * ad4[t].w;
            }
            sv += __shfl_xor(sv, 16, 64); dv += __shfl_xor(dv, 16, 64);
            sv += __shfl_xor(sv, 32, 64); dv += __shfl_xor(dv, 32, 64);
            if (lane < 16) {
                sArr[node * 4 + w] = sv;
                dArr[node * 4 + w] = dv;
            }
        }
    }
}

// ---------------- fused once-per-call setup: padded CSR + seg bounds + gsum=0 -------
__global__ void setup_csr(const int* __restrict__ ei, const int* __restrict__ batch,
                          int* __restrict__ cnt, int* __restrict__ csrc,
                          int* __restrict__ start, float* __restrict__ gsum) {
    int gid = blockIdx.x * 256 + threadIdx.x;
    if (gid == 0) *gsum = 0.f;
    if (gid < N_EDGES) {
        int src = ei[gid], dst = ei[N_EDGES + gid];
        int slot = atomicAdd(&cnt[dst], 1);
        csrc[(size_t)dst * PADDEG + slot] = src;
    }
    if (gid < N_NODES) {
        int b1 = batch[gid];
        int b0 = (gid == 0) ? -1 : batch[gid - 1];
        for (int b = b0 + 1; b <= b1; ++b) start[b] = gid;
        if (gid == N_NODES - 1)
            for (int b = b1 + 1; b <= N_B; ++b) start[b] = N_NODES;
    }
}

// ---------------- fused alpha + gather: FOUR dst nodes per wave (round-16 form) -----
template<bool POOL>
__launch_bounds__(256)
__global__ void gat_gather(const int* __restrict__ cnt, const int* __restrict__ csrc,
                           const float* __restrict__ sArr, const float* __restrict__ dArr,
                           const unsigned short* __restrict__ hfull, // [N,256] bf16
                           const float* __restrict__ bias,
                           const float* __restrict__ poolW, const float* __restrict__ poolB,
                           float* __restrict__ xout,
                           float* __restrict__ logit, float* __restrict__ pmax) {
    constexpr int CAP = PADDEG;
    __shared__ float qbuf[4][4][CAP * 4];
    __shared__ int   sbuf[4][4][CAP];
    __shared__ float red[16];

    const int wid = threadIdx.x >> 6;
    const int lane = threadIdx.x & 63;
    const int nl = lane >> 4;            // node within wave (0..3)
    const int sub = lane & 15;
    const int n = blockIdx.x * 16 + wid * 4 + nl;

    const int jb = n * PADDEG;
    const int deg = cnt[n];

    // ---- phase 1: q = exp(lrelu(s+d)), Z accumulate ----
    const int hh = sub & 3;
    const int slot = sub >> 2;           // 0..3
    const float dv = dArr[n * 4 + hh];
    const float qself = expf(lrelu(sArr[n * 4 + hh] + dv));
    float zp = 0.f;

    for (int base = 0; base < deg; base += 4) {
        int s = base + slot;
        if (s < deg) {
            int src = csrc[jb + s];
            float q = expf(lrelu(sArr[src * 4 + hh] + dv));
            qbuf[wid][nl][s * 4 + hh] = q;
            if (hh == 0) sbuf[wid][nl][s] = src;
            zp += q;
        }
    }
    zp += __shfl_xor(zp, 4, 64);
    zp += __shfl_xor(zp, 8, 64);
    const float inv = 0.25f / (zp + qself);
    __threadfence_block();

    // ---- phase 2: gather, 16 channels/lane, 2-deep ----
    const int h = sub >> 2;              // head of this lane's channels
    const int c16 = sub * 16;
    const int bl = (lane & 48) + h;      // lane in same node with hh==h, slot==0
    const float inv_g = __shfl(inv, bl, 64);
    const float qs_g  = __shfl(qself, bl, 64);

#define LOADU4(S, C) (*reinterpret_cast<const uint4*>(&hfull[(size_t)(unsigned)(S) * 256 + (C)]))
#define UNPK8(A, B, Q, U) { \
    A[B + 0] = fmaf((Q), __uint_as_float((U).x << 16),          A[B + 0]); \
    A[B + 1] = fmaf((Q), __uint_as_float((U).x & 0xFFFF0000u),  A[B + 1]); \
    A[B + 2] = fmaf((Q), __uint_as_float((U).y << 16),          A[B + 2]); \
    A[B + 3] = fmaf((Q), __uint_as_float((U).y & 0xFFFF0000u),  A[B + 3]); \
    A[B + 4] = fmaf((Q), __uint_as_float((U).z << 16),          A[B + 4]); \
    A[B + 5] = fmaf((Q), __uint_as_float((U).z & 0xFFFF0000u),  A[B + 5]); \
    A[B + 6] = fmaf((Q), __uint_as_float((U).w << 16),          A[B + 6]); \
    A[B + 7] = fmaf((Q), __uint_as_float((U).w & 0xFFFF0000u),  A[B + 7]); }

    float acc[16] = {0, 0, 0, 0, 0, 0, 0, 0, 0, 0, 0, 0, 0, 0, 0, 0};
    {
        uint4 ua = LOADU4(n, c16);
        uint4 ub = LOADU4(n, c16 + 8);
        UNPK8(acc, 0, qs_g, ua);
        UNPK8(acc, 8, qs_g, ub);
    }
    int s = 0;
    for (; s + 1 < deg; s += 2) {
        int s0 = sbuf[wid][nl][s], s1 = sbuf[wid][nl][s + 1];
        float q0 = qbuf[wid][nl][s * 4 + h];
        float q1 = qbuf[wid][nl][(s + 1) * 4 + h];
        uint4 u0a = LOADU4(s0, c16);
        uint4 u0b = LOADU4(s0, c16 + 8);
        uint4 u1a = LOADU4(s1, c16);
        uint4 u1b = LOADU4(s1, c16 + 8);
        UNPK8(acc, 0, q0, u0a);
        UNPK8(acc, 8, q0, u0b);
        UNPK8(acc, 0, q1, u1a);
        UNPK8(acc, 8, q1, u1b);
    }
    if (s < deg) {
        int s0 = sbuf[wid][nl][s];
        float q0 = qbuf[wid][nl][s * 4 + h];
        uint4 u0a = LOADU4(s0, c16);
        uint4 u0b = LOADU4(s0, c16 + 8);
        UNPK8(acc, 0, q0, u0a);
        UNPK8(acc, 8, q0, u0b);
    }
#undef UNPK8
#undef LOADU4

    // normalize by this head's 1/Z, then head-mean across the 4 head groups (bits 2,3)
#pragma unroll
    for (int j = 0; j < 16; ++j) acc[j] *= inv_g;
#pragma unroll
    for (int j = 0; j < 16; ++j) {
        acc[j] += __shfl_xor(acc[j], 4, 64);
        acc[j] += __shfl_xor(acc[j], 8, 64);
    }

    // lane (h, q=sub&3) finishes 4 contiguous channels cc = q*16 + h*4
    const int qq = sub & 3;
    const int cc = qq * 16 + h * 4;
    float v0 = (h == 0) ? acc[0] : (h == 1) ? acc[4] : (h == 2) ? acc[8]  : acc[12];
    float v1 = (h == 0) ? acc[1] : (h == 1) ? acc[5] : (h == 2) ? acc[9]  : acc[13];
    float v2 = (h == 0) ? acc[2] : (h == 1) ? acc[6] : (h == 2) ? acc[10] : acc[14];
    float v3 = (h == 0) ? acc[3] : (h == 1) ? acc[7] : (h == 2) ? acc[11] : acc[15];
    const float4 b4 = *reinterpret_cast<const float4*>(&bias[cc]);
    float4 o4;
    o4.x = gelu_exact(v0 + b4.x);
    o4.y = gelu_exact(v1 + b4.y);
    o4.z = gelu_exact(v2 + b4.z);
    o4.w = gelu_exact(v3 + b4.w);
    *reinterpret_cast<float4*>(&xout[(size_t)n * 64 + cc]) = o4;

    if (POOL) {
        const float4 pw = *reinterpret_cast<const float4*>(&poolW[cc]);
        float p = o4.x * pw.x + o4.y * pw.y + o4.z * pw.z + o4.w * pw.w;
#pragma unroll
        for (int of = 1; of < 16; of <<= 1) p += __shfl_xor(p, of, 64);
        float lg = p + poolB[0];
        if (sub == 0) {
            logit[n] = lg;
            red[wid * 4 + nl] = lg;
        }
        __syncthreads();
        if (threadIdx.x == 0) {
            float mm = red[0];
#pragma unroll
            for (int i = 1; i < 16; ++i) mm = fmaxf(mm, red[i]);
            pmax[blockIdx.x] = mm;
        }
    }
}

// ---------------- per-graph pooling with inline global-max over pmax ----------------
__global__ void pool_graph(const float* __restrict__ h3,
                           const float* __restrict__ logit,
                           const float* __restrict__ pmax,
                           const int* __restrict__ start,
                           float* __restrict__ pooled,
                           float* __restrict__ gsum) {
    __shared__ float gred[256];
    __shared__ float sacc[4][64];
    __shared__ float sw[4];
    int b = blockIdx.x;
    int lane = threadIdx.x & 63, wid = threadIdx.x >> 6;

    // inline global max over pmax[NPMAX]
    float m = -INFINITY;
    for (int i = threadIdx.x; i < NPMAX; i += 256) m = fmaxf(m, pmax[i]);
    gred[threadIdx.x] = m;
    __syncthreads();
    for (int s = 128; s > 0; s >>= 1) {
        if (threadIdx.x < s) gred[threadIdx.x] = fmaxf(gred[threadIdx.x], gred[threadIdx.x + s]);
        __syncthreads();
    }
    const float M = gred[0];

    int s = start[b], e = start[b + 1];
    float acc = 0.f, wsum = 0.f;
    for (int n = s + wid; n < e; n += 4) {
        float w = expf(logit[n] - M);
        acc += h3[(size_t)n * 64 + lane] * w;
        if (lane == 0) wsum += w;
    }
    sacc[wid][lane] = acc;
    if (lane == 0) sw[wid] = wsum;
    __syncthreads();
    if (wid == 0) {
        pooled[(size_t)b * 64 + lane] = sacc[0][lane] + sacc[1][lane] + sacc[2][lane] + sacc[3][lane];
        if (lane == 0) atomicAdd(gsum, sw[0] + sw[1] + sw[2] + sw[3]);
    }
}

// ---------------- head1 split-K part: 8 graphs/block --------------------------------
constexpr int GB1  = 8;
constexpr int KSEG = 372;   // 744 = 2 segments of 372 (93 aligned float4)

__launch_bounds__(256, 4)
__global__ void head1_part(const float* __restrict__ pooled, const float* __restrict__ gsum,
                           const float* __restrict__ rnafm, const float* __restrict__ hand,
                           const float* __restrict__ e1W,
                           float* __restrict__ part) {   // [2][N_B][256]
    __shared__ __align__(16) float fused[GB1][KSEG + 4];
    const int bq = blockIdx.x >> 1;
    const int ks = blockIdx.x & 1;
    const int g0 = bq * GB1;
    const int k0 = ks * KSEG;
    const int tid = threadIdx.x;
    const float inv = 1.0f / *gsum;

    for (int idx = tid; idx < GB1 * KSEG; idx += 256) {
        int g = idx / KSEG, kk = idx - g * KSEG;
        int k = kk + k0;
        int b = g0 + g;
        float v;
        if (k < 64)       v = pooled[(size_t)b * 64 + k] * inv;
        else if (k < 704) v = rnafm[(size_t)b * 640 + (k - 64)];
        else              v = hand[(size_t)b * 40 + (k - 704)];
        fused[g][kk] = v;
    }
    __syncthreads();

    const float* wr = e1W + (size_t)tid * 744 + k0;
    float a0 = 0.f, a1 = 0.f, a2 = 0.f, a3 = 0.f;
    float a4 = 0.f, a5 = 0.f, a6 = 0.f, a7 = 0.f;
    for (int q = 0; q < KSEG / 4; ++q) {
        float4 w4 = *reinterpret_cast<const float4*>(wr + q * 4);
        float4 f0 = *reinterpret_cast<const float4*>(&fused[0][q * 4]);
        float4 f1 = *reinterpret_cast<const float4*>(&fused[1][q * 4]);
        float4 f2 = *reinterpret_cast<const float4*>(&fused[2][q * 4]);
        float4 f3 = *reinterpret_cast<const float4*>(&fused[3][q * 4]);
        float4 f4 = *reinterpret_cast<const float4*>(&fused[4][q * 4]);
        float4 f5 = *reinterpret_cast<const float4*>(&fused[5][q * 4]);
        float4 f6 = *reinterpret_cast<const float4*>(&fused[6][q * 4]);
        float4 f7 = *reinterpret_cast<const float4*>(&fused[7][q * 4]);
        a0 += f0.x * w4.x + f0.y * w4.y + f0.z * w4.z + f0.w * w4.w;
        a1 += f1.x * w4.x + f1.y * w4.y + f1.z * w4.z + f1.w * w4.w;
        a2 += f2.x * w4.x + f2.y * w4.y + f2.z * w4.z + f2.w * w4.w;
        a3 += f3.x * w4.x + f3.y * w4.y + f3.z * w4.z + f3.w * w4.w;
        a4 += f4.x * w4.x + f4.y * w4.y + f4.z * w4.z + f4.w * w4.w;
        a5 += f5.x * w4.x + f5.y * w4.y + f5.z * w4.z + f5.w * w4.w;
        a6 += f6.x * w4.x + f6.y * w4.y + f6.z * w4.z + f6.w * w4.w;
        a7 += f7.x * w4.x + f7.y * w4.y + f7.z * w4.z + f7.w * w4.w;
    }
    float* po = part + ((size_t)ks * N_B + g0) * 256 + tid;
    po[0 * 256] = a0; po[1 * 256] = a1; po[2 * 256] = a2; po[3 * 256] = a3;
    po[4 * 256] = a4; po[5 * 256] = a5; po[6 * 256] = a6; po[7 * 256] = a7;
}

// ---------------- fused head tail: LN + e2 + {binary, per, cls}, 4 graphs/block ------
__launch_bounds__(256, 2)
__global__ void head_fused(const float* __restrict__ part,
                           const float* __restrict__ e1b,
                           const float* __restrict__ lng, const float* __restrict__ lnb,
                           const float* __restrict__ e2W, const float* __restrict__ e2b,
                           const float* __restrict__ binW, const float* __restrict__ binB,
                           const float* __restrict__ ad1W, const float* __restrict__ ad1b,
                           const float* __restrict__ ad2W, const float* __restrict__ ad2b,
                           const float* __restrict__ c1W, const float* __restrict__ c1b,
                           const float* __restrict__ c2W, const float* __restrict__ c2b,
                           float* __restrict__ out) {
    __shared__ float zr[4][256];
    __shared__ float red1[4][4], red2[4][4];
    __shared__ float sv[4][128];
    __shared__ float t64[4][64];
    __shared__ float h1s[4][5][32];
    __shared__ float binred[4][32];
    const int b0 = blockIdx.x * 4;
    const int tid = threadIdx.x;
    const int lane = tid & 63, wid = tid >> 6;

    // --- stage 1: z1 = LN(gelu(partA+partB+bias)) for 4 graphs, tid = channel ---
    const float eb = e1b[tid];
    float g0 = gelu_exact(part[(size_t)(b0 + 0) * 256 + tid] + part[((size_t)N_B + b0 + 0) * 256 + tid] + eb);
    float g1 = gelu_exact(part[(size_t)(b0 + 1) * 256 + tid] + part[((size_t)N_B + b0 + 1) * 256 + tid] + eb);
    float g2 = gelu_exact(part[(size_t)(b0 + 2) * 256 + tid] + part[((size_t)N_B + b0 + 2) * 256 + tid] + eb);
    float g3 = gelu_exact(part[(size_t)(b0 + 3) * 256 + tid] + part[((size_t)N_B + b0 + 3) * 256 + tid] + eb);

    float s10 = g0, s11 = g1, s12 = g2, s13 = g3;
    float s20 = g0 * g0, s21 = g1 * g1, s22 = g2 * g2, s23 = g3 * g3;
#pragma unroll
    for (int o = 1; o < 64; o <<= 1) {
        s10 += __shfl_xor(s10, o, 64); s11 += __shfl_xor(s11, o, 64);
        s12 += __shfl_xor(s12, o, 64); s13 += __shfl_xor(s13, o, 64);
        s20 += __shfl_xor(s20, o, 64); s21 += __shfl_xor(s21, o, 64);
        s22 += __shfl_xor(s22, o, 64); s23 += __shfl_xor(s23, o, 64);
    }
    if (lane == 0) {
        red1[wid][0] = s10; red1[wid][1] = s11; red1[wid][2] = s12; red1[wid][3] = s13;
        red2[wid][0] = s20; red2[wid][1] = s21; red2[wid][2] = s22; red2[wid][3] = s23;
    }
    __syncthreads();

    const float gN = lng[tid], bN = lnb[tid];
#pragma unroll
    for (int bb = 0; bb < 4; ++bb) {
        float s1 = red1[0][bb] + red1[1][bb] + red1[2][bb] + red1[3][bb];
        float s2 = red2[0][bb] + red2[1][bb] + red2[2][bb] + red2[3][bb];
        float mu  = s1 * (1.0f / 256.0f);
        float var = s2 * (1.0f / 256.0f) - mu * mu;
        float g = (bb == 0) ? g0 : (bb == 1) ? g1 : (bb == 2) ? g2 : g3;
        zr[bb][tid] = (g - mu) * rsqrtf(var + 1e-5f) * gN + bN;
    }
    __syncthreads();

    // --- stage 2: shr = gelu(z1 @ e2W^T + e2b); tid -> (ch = tid&127, gp = tid>>7) ---
    {
        const int ch = tid & 127, gp = tid >> 7;   // gp covers graphs gp*2, gp*2+1
        const float* wr = e2W + (size_t)ch * 256;
        const float e2bb = e2b[ch];
        float a0 = e2bb, a1 = e2bb;
        for (int k = 0; k < 256; k += 4) {
            float4 w4 = *reinterpret_cast<const float4*>(wr + k);
            float4 f0 = *reinterpret_cast<const float4*>(&zr[gp * 2][k]);
            float4 f1 = *reinterpret_cast<const float4*>(&zr[gp * 2 + 1][k]);
            a0 += f0.x * w4.x + f0.y * w4.y + f0.z * w4.z + f0.w * w4.w;
            a1 += f1.x * w4.x + f1.y * w4.y + f1.z * w4.z + f1.w * w4.w;
        }
        sv[gp * 2][ch]     = gelu_exact(a0);
        sv[gp * 2 + 1][ch] = gelu_exact(a1);
    }
    __syncthreads();

    // --- stage 3: t64 (c1), h1s (ad1), binary partials ---
    for (int idx = tid; idx < 256 + 640; idx += 256) {
        if (idx < 256) {
            int g = idx >> 6, ch = idx & 63;
            float a = c1b[ch];
            const float* wr = c1W + (size_t)ch * 128;
            for (int k = 0; k < 128; ++k) a += sv[g][k] * wr[k];
            t64[g][ch] = gelu_exact(a);
        } else {
            int j = idx - 256;
            int g = j / 160, r = j - g * 160;
            int e = r >> 5, hh = r & 31;
            float a = ad1b[e * 32 + hh];
            const float* wr = ad1W + (size_t)(e * 32 + hh) * 128;
            for (int k = 0; k < 128; ++k) a += sv[g][k] * wr[k];
            h1s[g][e][hh] = gelu_exact(a);
        }
    }
    if (tid < 128) {
        int g = tid >> 5, r = tid & 31;
        float a = 0.f;
#pragma unroll
        for (int k = 0; k < 4; ++k) a += sv[g][r * 4 + k] * binW[r * 4 + k];
        binred[g][r] = a;
    }
    __syncthreads();

    // --- stage 4: finals ---
    if (tid < 24) {            // cls: 6 x 4 graphs
        int g = tid / 6, c = tid - g * 6;
        float a = c2b[c];
        const float* wr = c2W + (size_t)c * 64;
        for (int k = 0; k < 64; ++k) a += t64[g][k] * wr[k];
        out[4800 + (size_t)(b0 + g) * 6 + c] = a;
    }
    if (tid >= 32 && tid < 52) {  // per: 5 x 4 graphs
        int j = tid - 32;
        int g = j / 5, e = j - g * 5;
        float a = ad2b[e];
        const float* wr = ad2W + (size_t)e * 32;
        for (int k = 0; k < 32; ++k) a += h1s[g][e][k] * wr[k];
        out[800 + (size_t)e * 800 + (b0 + g)] = a;
    }
    if (tid >= 64 && tid < 68) {  // binary: 4 graphs
        int g = tid - 64;
        float a = binB[0];
        for (int r = 0; r < 32; ++r) a += binred[g][r];
        out[b0 + g] = a;
    }
}

extern "C" void kernel_launch(void* const* d_in, const int* in_sizes, int n_in,
                              void* d_out, int out_size, void* d_ws, size_t ws_size,
                              hipStream_t stream) {
    const float* x       = (const float*)d_in[0];
    const int*   ei      = (const int*)d_in[1];
    const int*   batch   = (const int*)d_in[2];
    const float* rnafm   = (const float*)d_in[3];
    const float* hand    = (const float*)d_in[4];
    const float* gW[3]  = {(const float*)d_in[5],  (const float*)d_in[9],  (const float*)d_in[13]};
    const float* gAs[3] = {(const float*)d_in[6],  (const float*)d_in[10], (const float*)d_in[14]};
    const float* gAd[3] = {(const float*)d_in[7],  (const float*)d_in[11], (const float*)d_in[15]};
    const float* gB[3]  = {(const float*)d_in[8],  (const float*)d_in[12], (const float*)d_in[16]};
    const float* poolW = (const float*)d_in[17];
    const float* poolB = (const float*)d_in[18];
    const float* e1W = (const float*)d_in[19]; const float* e1b = (const float*)d_in[20];
    const float* lng = (const float*)d_in[21]; const float* lnb = (const float*)d_in[22];
    const float* e2W = (const float*)d_in[23]; const float* e2b = (const float*)d_in[24];
    const float* binW = (const float*)d_in[25]; const float* binB = (const float*)d_in[26];
    const float* ad1W = (const float*)d_in[27]; const float* ad1b = (const float*)d_in[28];
    const float* ad2W = (const float*)d_in[29]; const float* ad2b = (const float*)d_in[30];
    const float* c1W = (const float*)d_in[31]; const float* c1b = (const float*)d_in[32];
    const float* c2W = (const float*)d_in[33]; const float* c2b = (const float*)d_in[34];
    float* out = (float*)d_out;

    float* ws = (float*)d_ws;
    size_t off = 0;
    unsigned short* hfull = (unsigned short*)(ws + off); off += (size_t)N_NODES * 128; // bf16 [N,256]
    float* xcur   = ws + off; off += (size_t)N_NODES * 64;
    float* sArr   = ws + off; off += (size_t)N_NODES * 4;
    float* dArr   = ws + off; off += (size_t)N_NODES * 4;
    int*   cnt    = (int*)(ws + off); off += N_NODES;
    int*   csrc   = (int*)(ws + off); off += (size_t)N_NODES * PADDEG;
    float* logit  = ws + off; off += N_NODES;
    float* pmax   = ws + off; off += NPMAX;
    float* pooled = ws + off; off += (size_t)N_B * 64;
    float* part   = ws + off; off += (size_t)2 * N_B * 256;
    int*   start  = (int*)(ws + off); off += (N_B + 1);
    float* gsum   = ws + off; off += 1;

    // ---- one-time per call: padded CSR + segment bounds + gsum=0 (fused) ----
    hipMemsetAsync(cnt, 0, N_NODES * sizeof(int), stream);
    setup_csr<<<(N_EDGES + 255) / 256, 256, 0, stream>>>(ei, batch, cnt, csrc, start, gsum);

    // ---- 3 GAT layers ----
    for (int layer = 0; layer < 3; ++layer) {
        const float* xin = (layer == 0) ? x : xcur;
        if (layer == 0)
            gat_transform<21><<<512, 256, 0, stream>>>(xin, gW[0], gAs[0], gAd[0], hfull, sArr, dArr);
        else
            gat_transform<64><<<512, 256, 0, stream>>>(xin, gW[layer], gAs[layer], gAd[layer], hfull, sArr, dArr);
        if (layer < 2)
            gat_gather<false><<<N_NODES / 16, 256, 0, stream>>>(cnt, csrc, sArr, dArr, hfull,
                                                                gB[layer], nullptr, nullptr,
                                                                xcur, nullptr, nullptr);
        else
            gat_gather<true><<<N_NODES / 16, 256, 0, stream>>>(cnt, csrc, sArr, dArr, hfull,
                                                               gB[2], poolW, poolB,
                                                               xcur, logit, pmax);
    }

    // ---- pooling + heads ----
    pool_graph<<<N_B, 256, 0, stream>>>(xcur, logit, pmax, start, pooled, gsum);

    head1_part<<<(N_B / GB1) * 2, 256, 0, stream>>>(pooled, gsum, rnafm, hand, e1W, part);
    head_fused<<<N_B / 4, 256, 0, stream>>>(part, e1b, lng, lnb, e2W, e2b,
                                            binW, binB, ad1W, ad1b, ad2W, ad2b,
                                            c1W, c1b, c2W, c2b, out);
}

// Round 19
// 343.731 us; speedup vs baseline: 1.0324x; 1.0016x over previous
//
#include <hip/hip_runtime.h>
#include <hip/hip_bf16.h>
#include <math.h>

constexpr int N_NODES = 80000;
constexpr int N_EDGES = 480000;
constexpr int N_B     = 800;
constexpr int PADDEG  = 64;     // padded CSR row storage
constexpr int NPMAX   = N_NODES / 16;   // 5000 pmax entries

typedef __attribute__((ext_vector_type(8))) short bf16x8;
typedef __attribute__((ext_vector_type(4))) float f32x4;

__device__ __forceinline__ float gelu_exact(float x) {
    return 0.5f * x * (1.0f + erff(x * 0.70710678118654752f));
}
__device__ __forceinline__ float lrelu(float v) {
    return v > 0.f ? v : 0.2f * v;
}
// fp32 <-> bf16 (RNE)
__device__ __forceinline__ unsigned short f2bf(float f) {
    unsigned u = __float_as_uint(f);
    unsigned r = u + 0x7FFFu + ((u >> 16) & 1u);
    return (unsigned short)(r >> 16);
}
__device__ __forceinline__ float bf2f(unsigned short h) {
    return __uint_as_float(((unsigned)h) << 16);
}

// ---------------- GAT node transform: MFMA bf16, D = W·X^T --------------------------
template<int IN_DIM>
__launch_bounds__(256, 2)
__global__ void gat_transform(const float* __restrict__ xin,
                              const float* __restrict__ W,    // [256, IN_DIM] row-major
                              const float* __restrict__ aS,   // [256]
                              const float* __restrict__ aD,
                              unsigned short* __restrict__ hfull,  // [N,256] bf16
                              float* __restrict__ sArr,       // [N,4]
                              float* __restrict__ dArr) {
    constexpr int K  = (IN_DIM + 31) & ~31;     // 32 or 64
    constexpr int KS = K / 32;                  // k-steps
    constexpr int KP = K + 8;                   // +8 bf16 row pad
    __shared__ __align__(16) unsigned short Wb[256 * KP];
    __shared__ __align__(16) unsigned short xs[32 * KP];

    const int tid = threadIdx.x;
    const int lane = tid & 63, w = tid >> 6;

    for (int idx = tid; idx < 256 * K; idx += 256) {
        int c = idx / K, k = idx - c * K;
        Wb[c * KP + k] = (k < IN_DIM) ? f2bf(W[c * IN_DIM + k]) : (unsigned short)0;
    }
    __syncthreads();

    bf16x8 wfrag[4][KS];
    float4 as4[4], ad4[4];
#pragma unroll
    for (int t = 0; t < 4; ++t) {
        const int ch = w * 64 + t * 16 + (lane & 15);
#pragma unroll
        for (int s = 0; s < KS; ++s)
            wfrag[t][s] = *reinterpret_cast<const bf16x8*>(&Wb[ch * KP + s * 32 + (lane >> 4) * 8]);
        const int chb = w * 64 + t * 16 + (lane >> 4) * 4;   // channels this lane OUTPUTS
        as4[t] = *reinterpret_cast<const float4*>(&aS[chb]);
        ad4[t] = *reinterpret_cast<const float4*>(&aD[chb]);
    }

    const int ntiles = N_NODES / 32;
    for (int tile = blockIdx.x; tile < ntiles; tile += gridDim.x) {
        const int n0 = tile * 32;
        __syncthreads();
        for (int idx = tid; idx < 32 * K; idx += 256) {
            int r = idx / K, k = idx - r * K;
            xs[r * KP + k] = (k < IN_DIM) ? f2bf(xin[(size_t)(n0 + r) * IN_DIM + k])
                                          : (unsigned short)0;
        }
        __syncthreads();

#pragma unroll
        for (int m = 0; m < 2; ++m) {
            bf16x8 xfrag[KS];
#pragma unroll
            for (int s = 0; s < KS; ++s)
                xfrag[s] = *reinterpret_cast<const bf16x8*>(
                    &xs[(m * 16 + (lane & 15)) * KP + s * 32 + (lane >> 4) * 8]);

            const int node = n0 + m * 16 + (lane & 15);
            float sv = 0.f, dv = 0.f;
#pragma unroll
            for (int t = 0; t < 4; ++t) {
                f32x4 a = {0.f, 0.f, 0.f, 0.f};
#pragma unroll
                for (int s = 0; s < KS; ++s)
                    a = __builtin_amdgcn_mfma_f32_16x16x32_bf16(wfrag[t][s], xfrag[s], a, 0, 0, 0);
                ushort4 hb;
                hb.x = f2bf(a[0]); hb.y = f2bf(a[1]); hb.z = f2bf(a[2]); hb.w = f2bf(a[3]);
                const int chb = w * 64 + t * 16 + (lane >> 4) * 4;
                *reinterpret_cast<ushort4*>(&hfull[(size_t)node * 256 + chb]) = hb;
                sv += a[0] * as4[t].x + a[1] * as4[t].y + a[2] * as4[t].z + a[3] * as4[t].w;
                dv += a[0] * ad4[t].x + a[1] * ad4[t].y + a[2] * ad4[t].z + a[3] * ad4[t].w;
            }
            sv += __shfl_xor(sv, 16, 64); dv += __shfl_xor(dv, 16, 64);
            sv += __shfl_xor(sv, 32, 64); dv += __shfl_xor(dv, 32, 64);
            if (lane < 16) {
                sArr[node * 4 + w] = sv;
                dArr[node * 4 + w] = dv;
            }
        }
    }
}

// ---------------- fused once-per-call setup: padded CSR + seg bounds + gsum=0 -------
__global__ void setup_csr(const int* __restrict__ ei, const int* __restrict__ batch,
                          int* __restrict__ cnt, int* __restrict__ csrc,
                          int* __restrict__ start, float* __restrict__ gsum) {
    int gid = blockIdx.x * 256 + threadIdx.x;
    if (gid == 0) *gsum = 0.f;
    if (gid < N_EDGES) {
        int src = ei[gid], dst = ei[N_EDGES + gid];
        int slot = atomicAdd(&cnt[dst], 1);
        csrc[(size_t)dst * PADDEG + slot] = src;
    }
    if (gid < N_NODES) {
        int b1 = batch[gid];
        int b0 = (gid == 0) ? -1 : batch[gid - 1];
        for (int b = b0 + 1; b <= b1; ++b) start[b] = gid;
        if (gid == N_NODES - 1)
            for (int b = b1 + 1; b <= N_B; ++b) start[b] = N_NODES;
    }
}

// ---------------- fused alpha + gather: FOUR dst nodes per wave, CAP=32 LDS ---------
// LDS halved (CAP 64->32): occupancy ceiling 8 blocks/CU. Overflow (deg>CAP,
// never for Poisson(6) input) handled correctly via global recompute fallback.
template<bool POOL>
__launch_bounds__(256)
__global__ void gat_gather(const int* __restrict__ cnt, const int* __restrict__ csrc,
                           const float* __restrict__ sArr, const float* __restrict__ dArr,
                           const unsigned short* __restrict__ hfull, // [N,256] bf16
                           const float* __restrict__ bias,
                           const float* __restrict__ poolW, const float* __restrict__ poolB,
                           float* __restrict__ xout,
                           float* __restrict__ logit, float* __restrict__ pmax) {
    constexpr int CAP = 32;
    __shared__ float qbuf[4][4][CAP * 4];
    __shared__ int   sbuf[4][4][CAP];
    __shared__ float red[16];

    const int wid = threadIdx.x >> 6;
    const int lane = threadIdx.x & 63;
    const int nl = lane >> 4;            // node within wave (0..3)
    const int sub = lane & 15;
    const int n = blockIdx.x * 16 + wid * 4 + nl;

    const int jb = n * PADDEG;
    const int deg = cnt[n];

    // ---- phase 1: q = exp(lrelu(s+d)), Z accumulate ----
    const int hh = sub & 3;
    const int slot = sub >> 2;           // 0..3
    const float dv = dArr[n * 4 + hh];
    const float qself = expf(lrelu(sArr[n * 4 + hh] + dv));
    float zp = 0.f;

    for (int base = 0; base < deg; base += 4) {
        int s = base + slot;
        if (s < deg) {
            int src = csrc[jb + s];
            float q = expf(lrelu(sArr[src * 4 + hh] + dv));
            if (s < CAP) {
                qbuf[wid][nl][s * 4 + hh] = q;
                if (hh == 0) sbuf[wid][nl][s] = src;
            }
            zp += q;
        }
    }
    zp += __shfl_xor(zp, 4, 64);
    zp += __shfl_xor(zp, 8, 64);
    const float inv = 0.25f / (zp + qself);
    __threadfence_block();

    // ---- phase 2: gather, 16 channels/lane, 2-deep ----
    const int h = sub >> 2;              // head of this lane's channels
    const int c16 = sub * 16;
    const int bl = (lane & 48) + h;      // lane in same node with hh==h, slot==0
    const float inv_g = __shfl(inv, bl, 64);
    const float qs_g  = __shfl(qself, bl, 64);
    const int dcap = deg < CAP ? deg : CAP;

#define LOADU4(S, C) (*reinterpret_cast<const uint4*>(&hfull[(size_t)(unsigned)(S) * 256 + (C)]))
#define UNPK8(A, B, Q, U) { \
    A[B + 0] = fmaf((Q), __uint_as_float((U).x << 16),          A[B + 0]); \
    A[B + 1] = fmaf((Q), __uint_as_float((U).x & 0xFFFF0000u),  A[B + 1]); \
    A[B + 2] = fmaf((Q), __uint_as_float((U).y << 16),          A[B + 2]); \
    A[B + 3] = fmaf((Q), __uint_as_float((U).y & 0xFFFF0000u),  A[B + 3]); \
    A[B + 4] = fmaf((Q), __uint_as_float((U).z << 16),          A[B + 4]); \
    A[B + 5] = fmaf((Q), __uint_as_float((U).z & 0xFFFF0000u),  A[B + 5]); \
    A[B + 6] = fmaf((Q), __uint_as_float((U).w << 16),          A[B + 6]); \
    A[B + 7] = fmaf((Q), __uint_as_float((U).w & 0xFFFF0000u),  A[B + 7]); }

    float acc[16] = {0, 0, 0, 0, 0, 0, 0, 0, 0, 0, 0, 0, 0, 0, 0, 0};
    {
        uint4 ua = LOADU4(n, c16);
        uint4 ub = LOADU4(n, c16 + 8);
        UNPK8(acc, 0, qs_g, ua);
        UNPK8(acc, 8, qs_g, ub);
    }
    int s = 0;
    for (; s + 1 < dcap; s += 2) {
        int s0 = sbuf[wid][nl][s], s1 = sbuf[wid][nl][s + 1];
        float q0 = qbuf[wid][nl][s * 4 + h];
        float q1 = qbuf[wid][nl][(s + 1) * 4 + h];
        uint4 u0a = LOADU4(s0, c16);
        uint4 u0b = LOADU4(s0, c16 + 8);
        uint4 u1a = LOADU4(s1, c16);
        uint4 u1b = LOADU4(s1, c16 + 8);
        UNPK8(acc, 0, q0, u0a);
        UNPK8(acc, 8, q0, u0b);
        UNPK8(acc, 0, q1, u1a);
        UNPK8(acc, 8, q1, u1b);
    }
    if (s < dcap) {
        int s0 = sbuf[wid][nl][s];
        float q0 = qbuf[wid][nl][s * 4 + h];
        uint4 u0a = LOADU4(s0, c16);
        uint4 u0b = LOADU4(s0, c16 + 8);
        UNPK8(acc, 0, q0, u0a);
        UNPK8(acc, 8, q0, u0b);
    }
    if (deg > CAP) {   // overflow fallback (never taken for this input): recompute q
        const float dvh = dArr[n * 4 + h];
        for (int t = CAP; t < deg; ++t) {
            int st = csrc[jb + t];
            float q = expf(lrelu(sArr[st * 4 + h] + dvh));
            uint4 ua = LOADU4(st, c16);
            uint4 ub = LOADU4(st, c16 + 8);
            UNPK8(acc, 0, q, ua);
            UNPK8(acc, 8, q, ub);
        }
    }
#undef UNPK8
#undef LOADU4

    // normalize by this head's 1/Z, then head-mean across the 4 head groups (bits 2,3)
#pragma unroll
    for (int j = 0; j < 16; ++j) acc[j] *= inv_g;
#pragma unroll
    for (int j = 0; j < 16; ++j) {
        acc[j] += __shfl_xor(acc[j], 4, 64);
        acc[j] += __shfl_xor(acc[j], 8, 64);
    }

    // lane (h, q=sub&3) finishes 4 contiguous channels cc = q*16 + h*4
    const int qq = sub & 3;
    const int cc = qq * 16 + h * 4;
    float v0 = (h == 0) ? acc[0] : (h == 1) ? acc[4] : (h == 2) ? acc[8]  : acc[12];
    float v1 = (h == 0) ? acc[1] : (h == 1) ? acc[5] : (h == 2) ? acc[9]  : acc[13];
    float v2 = (h == 0) ? acc[2] : (h == 1) ? acc[6] : (h == 2) ? acc[10] : acc[14];
    float v3 = (h == 0) ? acc[3] : (h == 1) ? acc[7] : (h == 2) ? acc[11] : acc[15];
    const float4 b4 = *reinterpret_cast<const float4*>(&bias[cc]);
    float4 o4;
    o4.x = gelu_exact(v0 + b4.x);
    o4.y = gelu_exact(v1 + b4.y);
    o4.z = gelu_exact(v2 + b4.z);
    o4.w = gelu_exact(v3 + b4.w);
    *reinterpret_cast<float4*>(&xout[(size_t)n * 64 + cc]) = o4;

    if (POOL) {
        const float4 pw = *reinterpret_cast<const float4*>(&poolW[cc]);
        float p = o4.x * pw.x + o4.y * pw.y + o4.z * pw.z + o4.w * pw.w;
#pragma unroll
        for (int of = 1; of < 16; of <<= 1) p += __shfl_xor(p, of, 64);
        float lg = p + poolB[0];
        if (sub == 0) {
            logit[n] = lg;
            red[wid * 4 + nl] = lg;
        }
        __syncthreads();
        if (threadIdx.x == 0) {
            float mm = red[0];
#pragma unroll
            for (int i = 1; i < 16; ++i) mm = fmaxf(mm, red[i]);
            pmax[blockIdx.x] = mm;
        }
    }
}

// ---------------- per-graph pooling with inline global-max over pmax ----------------
__global__ void pool_graph(const float* __restrict__ h3,
                           const float* __restrict__ logit,
                           const float* __restrict__ pmax,
                           const int* __restrict__ start,
                           float* __restrict__ pooled,
                           float* __restrict__ gsum) {
    __shared__ float gred[256];
    __shared__ float sacc[4][64];
    __shared__ float sw[4];
    int b = blockIdx.x;
    int lane = threadIdx.x & 63, wid = threadIdx.x >> 6;

    float m = -INFINITY;
    for (int i = threadIdx.x; i < NPMAX; i += 256) m = fmaxf(m, pmax[i]);
    gred[threadIdx.x] = m;
    __syncthreads();
    for (int s = 128; s > 0; s >>= 1) {
        if (threadIdx.x < s) gred[threadIdx.x] = fmaxf(gred[threadIdx.x], gred[threadIdx.x + s]);
        __syncthreads();
    }
    const float M = gred[0];

    int s = start[b], e = start[b + 1];
    float acc = 0.f, wsum = 0.f;
    for (int n = s + wid; n < e; n += 4) {
        float w = expf(logit[n] - M);
        acc += h3[(size_t)n * 64 + lane] * w;
        if (lane == 0) wsum += w;
    }
    sacc[wid][lane] = acc;
    if (lane == 0) sw[wid] = wsum;
    __syncthreads();
    if (wid == 0) {
        pooled[(size_t)b * 64 + lane] = sacc[0][lane] + sacc[1][lane] + sacc[2][lane] + sacc[3][lane];
        if (lane == 0) atomicAdd(gsum, sw[0] + sw[1] + sw[2] + sw[3]);
    }
}

// ---------------- head1 split-K part: 8 graphs/block --------------------------------
constexpr int GB1  = 8;
constexpr int KSEG = 372;   // 744 = 2 segments of 372 (93 aligned float4)

__launch_bounds__(256, 4)
__global__ void head1_part(const float* __restrict__ pooled, const float* __restrict__ gsum,
                           const float* __restrict__ rnafm, const float* __restrict__ hand,
                           const float* __restrict__ e1W,
                           float* __restrict__ part) {   // [2][N_B][256]
    __shared__ __align__(16) float fused[GB1][KSEG + 4];
    const int bq = blockIdx.x >> 1;
    const int ks = blockIdx.x & 1;
    const int g0 = bq * GB1;
    const int k0 = ks * KSEG;
    const int tid = threadIdx.x;
    const float inv = 1.0f / *gsum;

    for (int idx = tid; idx < GB1 * KSEG; idx += 256) {
        int g = idx / KSEG, kk = idx - g * KSEG;
        int k = kk + k0;
        int b = g0 + g;
        float v;
        if (k < 64)       v = pooled[(size_t)b * 64 + k] * inv;
        else if (k < 704) v = rnafm[(size_t)b * 640 + (k - 64)];
        else              v = hand[(size_t)b * 40 + (k - 704)];
        fused[g][kk] = v;
    }
    __syncthreads();

    const float* wr = e1W + (size_t)tid * 744 + k0;
    float a0 = 0.f, a1 = 0.f, a2 = 0.f, a3 = 0.f;
    float a4 = 0.f, a5 = 0.f, a6 = 0.f, a7 = 0.f;
    for (int q = 0; q < KSEG / 4; ++q) {
        float4 w4 = *reinterpret_cast<const float4*>(wr + q * 4);
        float4 f0 = *reinterpret_cast<const float4*>(&fused[0][q * 4]);
        float4 f1 = *reinterpret_cast<const float4*>(&fused[1][q * 4]);
        float4 f2 = *reinterpret_cast<const float4*>(&fused[2][q * 4]);
        float4 f3 = *reinterpret_cast<const float4*>(&fused[3][q * 4]);
        float4 f4 = *reinterpret_cast<const float4*>(&fused[4][q * 4]);
        float4 f5 = *reinterpret_cast<const float4*>(&fused[5][q * 4]);
        float4 f6 = *reinterpret_cast<const float4*>(&fused[6][q * 4]);
        float4 f7 = *reinterpret_cast<const float4*>(&fused[7][q * 4]);
        a0 += f0.x * w4.x + f0.y * w4.y + f0.z * w4.z + f0.w * w4.w;
        a1 += f1.x * w4.x + f1.y * w4.y + f1.z * w4.z + f1.w * w4.w;
        a2 += f2.x * w4.x + f2.y * w4.y + f2.z * w4.z + f2.w * w4.w;
        a3 += f3.x * w4.x + f3.y * w4.y + f3.z * w4.z + f3.w * w4.w;
        a4 += f4.x * w4.x + f4.y * w4.y + f4.z * w4.z + f4.w * w4.w;
        a5 += f5.x * w4.x + f5.y * w4.y + f5.z * w4.z + f5.w * w4.w;
        a6 += f6.x * w4.x + f6.y * w4.y + f6.z * w4.z + f6.w * w4.w;
        a7 += f7.x * w4.x + f7.y * w4.y + f7.z * w4.z + f7.w * w4.w;
    }
    float* po = part + ((size_t)ks * N_B + g0) * 256 + tid;
    po[0 * 256] = a0; po[1 * 256] = a1; po[2 * 256] = a2; po[3 * 256] = a3;
    po[4 * 256] = a4; po[5 * 256] = a5; po[6 * 256] = a6; po[7 * 256] = a7;
}

// ---------------- fused head tail: LN + e2 + {binary, per, cls}, 4 graphs/block ------
__launch_bounds__(256, 2)
__global__ void head_fused(const float* __restrict__ part,
                           const float* __restrict__ e1b,
                           const float* __restrict__ lng, const float* __restrict__ lnb,
                           const float* __restrict__ e2W, const float* __restrict__ e2b,
                           const float* __restrict__ binW, const float* __restrict__ binB,
                           const float* __restrict__ ad1W, const float* __restrict__ ad1b,
                           const float* __restrict__ ad2W, const float* __restrict__ ad2b,
                           const float* __restrict__ c1W, const float* __restrict__ c1b,
                           const float* __restrict__ c2W, const float* __restrict__ c2b,
                           float* __restrict__ out) {
    __shared__ float zr[4][256];
    __shared__ float red1[4][4], red2[4][4];
    __shared__ float sv[4][128];
    __shared__ float t64[4][64];
    __shared__ float h1s[4][5][32];
    __shared__ float binred[4][32];
    const int b0 = blockIdx.x * 4;
    const int tid = threadIdx.x;
    const int lane = tid & 63, wid = tid >> 6;

    const float eb = e1b[tid];
    float g0 = gelu_exact(part[(size_t)(b0 + 0) * 256 + tid] + part[((size_t)N_B + b0 + 0) * 256 + tid] + eb);
    float g1 = gelu_exact(part[(size_t)(b0 + 1) * 256 + tid] + part[((size_t)N_B + b0 + 1) * 256 + tid] + eb);
    float g2 = gelu_exact(part[(size_t)(b0 + 2) * 256 + tid] + part[((size_t)N_B + b0 + 2) * 256 + tid] + eb);
    float g3 = gelu_exact(part[(size_t)(b0 + 3) * 256 + tid] + part[((size_t)N_B + b0 + 3) * 256 + tid] + eb);

    float s10 = g0, s11 = g1, s12 = g2, s13 = g3;
    float s20 = g0 * g0, s21 = g1 * g1, s22 = g2 * g2, s23 = g3 * g3;
#pragma unroll
    for (int o = 1; o < 64; o <<= 1) {
        s10 += __shfl_xor(s10, o, 64); s11 += __shfl_xor(s11, o, 64);
        s12 += __shfl_xor(s12, o, 64); s13 += __shfl_xor(s13, o, 64);
        s20 += __shfl_xor(s20, o, 64); s21 += __shfl_xor(s21, o, 64);
        s22 += __shfl_xor(s22, o, 64); s23 += __shfl_xor(s23, o, 64);
    }
    if (lane == 0) {
        red1[wid][0] = s10; red1[wid][1] = s11; red1[wid][2] = s12; red1[wid][3] = s13;
        red2[wid][0] = s20; red2[wid][1] = s21; red2[wid][2] = s22; red2[wid][3] = s23;
    }
    __syncthreads();

    const float gN = lng[tid], bN = lnb[tid];
#pragma unroll
    for (int bb = 0; bb < 4; ++bb) {
        float s1 = red1[0][bb] + red1[1][bb] + red1[2][bb] + red1[3][bb];
        float s2 = red2[0][bb] + red2[1][bb] + red2[2][bb] + red2[3][bb];
        float mu  = s1 * (1.0f / 256.0f);
        float var = s2 * (1.0f / 256.0f) - mu * mu;
        float g = (bb == 0) ? g0 : (bb == 1) ? g1 : (bb == 2) ? g2 : g3;
        zr[bb][tid] = (g - mu) * rsqrtf(var + 1e-5f) * gN + bN;
    }
    __syncthreads();

    {
        const int ch = tid & 127, gp = tid >> 7;   // gp covers graphs gp*2, gp*2+1
        const float* wr = e2W + (size_t)ch * 256;
        const float e2bb = e2b[ch];
        float a0 = e2bb, a1 = e2bb;
        for (int k = 0; k < 256; k += 4) {
            float4 w4 = *reinterpret_cast<const float4*>(wr + k);
            float4 f0 = *reinterpret_cast<const float4*>(&zr[gp * 2][k]);
            float4 f1 = *reinterpret_cast<const float4*>(&zr[gp * 2 + 1][k]);
            a0 += f0.x * w4.x + f0.y * w4.y + f0.z * w4.z + f0.w * w4.w;
            a1 += f1.x * w4.x + f1.y * w4.y + f1.z * w4.z + f1.w * w4.w;
        }
        sv[gp * 2][ch]     = gelu_exact(a0);
        sv[gp * 2 + 1][ch] = gelu_exact(a1);
    }
    __syncthreads();

    for (int idx = tid; idx < 256 + 640; idx += 256) {
        if (idx < 256) {
            int g = idx >> 6, ch = idx & 63;
            float a = c1b[ch];
            const float* wr = c1W + (size_t)ch * 128;
            for (int k = 0; k < 128; ++k) a += sv[g][k] * wr[k];
            t64[g][ch] = gelu_exact(a);
        } else {
            int j = idx - 256;
            int g = j / 160, r = j - g * 160;
            int e = r >> 5, hh = r & 31;
            float a = ad1b[e * 32 + hh];
            const float* wr = ad1W + (size_t)(e * 32 + hh) * 128;
            for (int k = 0; k < 128; ++k) a += sv[g][k] * wr[k];
            h1s[g][e][hh] = gelu_exact(a);
        }
    }
    if (tid < 128) {
        int g = tid >> 5, r = tid & 31;
        float a = 0.f;
#pragma unroll
        for (int k = 0; k < 4; ++k) a += sv[g][r * 4 + k] * binW[r * 4 + k];
        binred[g][r] = a;
    }
    __syncthreads();

    if (tid < 24) {            // cls: 6 x 4 graphs
        int g = tid / 6, c = tid - g * 6;
        float a = c2b[c];
        const float* wr = c2W + (size_t)c * 64;
        for (int k = 0; k < 64; ++k) a += t64[g][k] * wr[k];
        out[4800 + (size_t)(b0 + g) * 6 + c] = a;
    }
    if (tid >= 32 && tid < 52) {  // per: 5 x 4 graphs
        int j = tid - 32;
        int g = j / 5, e = j - g * 5;
        float a = ad2b[e];
        const float* wr = ad2W + (size_t)e * 32;
        for (int k = 0; k < 32; ++k) a += h1s[g][e][k] * wr[k];
        out[800 + (size_t)e * 800 + (b0 + g)] = a;
    }
    if (tid >= 64 && tid < 68) {  // binary: 4 graphs
        int g = tid - 64;
        float a = binB[0];
        for (int r = 0; r < 32; ++r) a += binred[g][r];
        out[b0 + g] = a;
    }
}

extern "C" void kernel_launch(void* const* d_in, const int* in_sizes, int n_in,
                              void* d_out, int out_size, void* d_ws, size_t ws_size,
                              hipStream_t stream) {
    const float* x       = (const float*)d_in[0];
    const int*   ei      = (const int*)d_in[1];
    const int*   batch   = (const int*)d_in[2];
    const float* rnafm   = (const float*)d_in[3];
    const float* hand    = (const float*)d_in[4];
    const float* gW[3]  = {(const float*)d_in[5],  (const float*)d_in[9],  (const float*)d_in[13]};
    const float* gAs[3] = {(const float*)d_in[6],  (const float*)d_in[10], (const float*)d_in[14]};
    const float* gAd[3] = {(const float*)d_in[7],  (const float*)d_in[11], (const float*)d_in[15]};
    const float* gB[3]  = {(const float*)d_in[8],  (const float*)d_in[12], (const float*)d_in[16]};
    const float* poolW = (const float*)d_in[17];
    const float* poolB = (const float*)d_in[18];
    const float* e1W = (const float*)d_in[19]; const float* e1b = (const float*)d_in[20];
    const float* lng = (const float*)d_in[21]; const float* lnb = (const float*)d_in[22];
    const float* e2W = (const float*)d_in[23]; const float* e2b = (const float*)d_in[24];
    const float* binW = (const float*)d_in[25]; const float* binB = (const float*)d_in[26];
    const float* ad1W = (const float*)d_in[27]; const float* ad1b = (const float*)d_in[28];
    const float* ad2W = (const float*)d_in[29]; const float* ad2b = (const float*)d_in[30];
    const float* c1W = (const float*)d_in[31]; const float* c1b = (const float*)d_in[32];
    const float* c2W = (const float*)d_in[33]; const float* c2b = (const float*)d_in[34];
    float* out = (float*)d_out;

    float* ws = (float*)d_ws;
    size_t off = 0;
    unsigned short* hfull = (unsigned short*)(ws + off); off += (size_t)N_NODES * 128; // bf16 [N,256]
    float* xcur   = ws + off; off += (size_t)N_NODES * 64;
    float* sArr   = ws + off; off += (size_t)N_NODES * 4;
    float* dArr   = ws + off; off += (size_t)N_NODES * 4;
    int*   cnt    = (int*)(ws + off); off += N_NODES;
    int*   csrc   = (int*)(ws + off); off += (size_t)N_NODES * PADDEG;
    float* logit  = ws + off; off += N_NODES;
    float* pmax   = ws + off; off += NPMAX;
    float* pooled = ws + off; off += (size_t)N_B * 64;
    float* part   = ws + off; off += (size_t)2 * N_B * 256;
    int*   start  = (int*)(ws + off); off += (N_B + 1);
    float* gsum   = ws + off; off += 1;

    // ---- one-time per call: padded CSR + segment bounds + gsum=0 (fused) ----
    hipMemsetAsync(cnt, 0, N_NODES * sizeof(int), stream);
    setup_csr<<<(N_EDGES + 255) / 256, 256, 0, stream>>>(ei, batch, cnt, csrc, start, gsum);

    // ---- 3 GAT layers ----
    for (int layer = 0; layer < 3; ++layer) {
        const float* xin = (layer == 0) ? x : xcur;
        if (layer == 0)
            gat_transform<21><<<512, 256, 0, stream>>>(xin, gW[0], gAs[0], gAd[0], hfull, sArr, dArr);
        else
            gat_transform<64><<<512, 256, 0, stream>>>(xin, gW[layer], gAs[layer], gAd[layer], hfull, sArr, dArr);
        if (layer < 2)
            gat_gather<false><<<N_NODES / 16, 256, 0, stream>>>(cnt, csrc, sArr, dArr, hfull,
                                                                gB[layer], nullptr, nullptr,
                                                                xcur, nullptr, nullptr);
        else
            gat_gather<true><<<N_NODES / 16, 256, 0, stream>>>(cnt, csrc, sArr, dArr, hfull,
                                                               gB[2], poolW, poolB,
                                                               xcur, logit, pmax);
    }

    // ---- pooling + heads ----
    pool_graph<<<N_B, 256, 0, stream>>>(xcur, logit, pmax, start, pooled, gsum);

    head1_part<<<(N_B / GB1) * 2, 256, 0, stream>>>(pooled, gsum, rnafm, hand, e1W, part);
    head_fused<<<N_B / 4, 256, 0, stream>>>(part, e1b, lng, lnb, e2W, e2b,
                                            binW, binB, ad1W, ad1b, ad2W, ad2b,
                                            c1W, c1b, c2W, c2b, out);
}

// Round 21
// 300.936 us; speedup vs baseline: 1.1792x; 1.1422x over previous
//
#include <hip/hip_runtime.h>
#include <hip/hip_bf16.h>
#include <math.h>

constexpr int N_NODES = 80000;
constexpr int N_EDGES = 480000;
constexpr int N_B     = 800;
constexpr int PADDEG  = 64;     // padded CSR row storage
constexpr int NPMAX   = N_NODES / 16;   // 5000 pmax entries

typedef __attribute__((ext_vector_type(8))) short bf16x8;
typedef __attribute__((ext_vector_type(4))) float f32x4;
typedef __attribute__((ext_vector_type(2))) float f32x2;

#if defined(__HIP_DEVICE_COMPILE__) && defined(__has_builtin)
#if __has_builtin(__builtin_amdgcn_cvt_pk_f32_fp8) && __has_builtin(__builtin_amdgcn_cvt_pk_fp8_f32)
#define HW_FP8 1
#endif
#endif

__device__ __forceinline__ float gelu_exact(float x) {
    return 0.5f * x * (1.0f + erff(x * 0.70710678118654752f));
}
__device__ __forceinline__ float lrelu(float v) {
    return v > 0.f ? v : 0.2f * v;
}
// fp32 <-> bf16 (RNE)
__device__ __forceinline__ unsigned short f2bf(float f) {
    unsigned u = __float_as_uint(f);
    unsigned r = u + 0x7FFFu + ((u >> 16) & 1u);
    return (unsigned short)(r >> 16);
}

// ---- fp8 e4m3 helpers: HW cvt on gfx950; pure-bit software fallback (host-safe) ----
__device__ __forceinline__ float dec8_sw(unsigned b) {
    unsigned s = (b >> 7) & 1u, e = (b >> 3) & 15u, m = b & 7u;
    float v = e ? __uint_as_float(((e + 120u) << 23) | (m << 20))
                : (float)m * 0.001953125f;           // subnormal: m * 2^-9
    return s ? -v : v;
}
__device__ __forceinline__ unsigned enc8_sw(float x) {
    unsigned u = __float_as_uint(x);
    unsigned s = u >> 31;
    u &= 0x7FFFFFFFu;
    if (__uint_as_float(u) > 448.f) u = __float_as_uint(448.f);
    unsigned byte;
    if (__uint_as_float(u) < 0.015625f) {            // < 2^-6: e4m3 subnormal
        int q = (int)rintf(__uint_as_float(u) * 512.f);   // units of 2^-9
        if (q > 7) q = 7;
        byte = (unsigned)q;
    } else {
        unsigned r = u + 0x7FFFFu + ((u >> 20) & 1u);    // RNE 23->3 mantissa bits
        int e = (int)(r >> 23) - 127;
        unsigned m = (r >> 20) & 7u;
        if (e > 8) { e = 8; m = 7u; }                    // clamp to 448
        byte = ((unsigned)(e + 7) << 3) | m;
    }
    return (s << 7) | byte;
}

template<bool HI>
__device__ __forceinline__ f32x2 fp8pair(unsigned u) {
#ifdef HW_FP8
    return __builtin_amdgcn_cvt_pk_f32_fp8((int)u, HI);
#else
    f32x2 v;
    v.x = dec8_sw((u >> (HI ? 16 : 0)) & 0xFFu);
    v.y = dec8_sw((u >> (HI ? 24 : 8)) & 0xFFu);
    return v;
#endif
}
__device__ __forceinline__ unsigned fp8pack4(float a0, float a1, float a2, float a3) {
#ifdef HW_FP8
    int p = __builtin_amdgcn_cvt_pk_fp8_f32(a0, a1, 0, false);
    p = __builtin_amdgcn_cvt_pk_fp8_f32(a2, a3, p, true);
    return (unsigned)p;
#else
    return enc8_sw(a0) | (enc8_sw(a1) << 8) | (enc8_sw(a2) << 16) | (enc8_sw(a3) << 24);
#endif
}

// ---------------- GAT node transform: MFMA bf16, D = W·X^T, fp8 hfull out -----------
template<int IN_DIM>
__launch_bounds__(256, 2)
__global__ void gat_transform(const float* __restrict__ xin,
                              const float* __restrict__ W,    // [256, IN_DIM] row-major
                              const float* __restrict__ aS,   // [256]
                              const float* __restrict__ aD,
                              unsigned char* __restrict__ hfull,   // [N,256] fp8 e4m3
                              float* __restrict__ sArr,       // [N,4]
                              float* __restrict__ dArr) {
    constexpr int K  = (IN_DIM + 31) & ~31;     // 32 or 64
    constexpr int KS = K / 32;                  // k-steps
    constexpr int KP = K + 8;                   // +8 bf16 row pad
    __shared__ __align__(16) unsigned short Wb[256 * KP];
    __shared__ __align__(16) unsigned short xs[32 * KP];

    const int tid = threadIdx.x;
    const int lane = tid & 63, w = tid >> 6;

    for (int idx = tid; idx < 256 * K; idx += 256) {
        int c = idx / K, k = idx - c * K;
        Wb[c * KP + k] = (k < IN_DIM) ? f2bf(W[c * IN_DIM + k]) : (unsigned short)0;
    }
    __syncthreads();

    bf16x8 wfrag[4][KS];
    float4 as4[4], ad4[4];
#pragma unroll
    for (int t = 0; t < 4; ++t) {
        const int ch = w * 64 + t * 16 + (lane & 15);
#pragma unroll
        for (int s = 0; s < KS; ++s)
            wfrag[t][s] = *reinterpret_cast<const bf16x8*>(&Wb[ch * KP + s * 32 + (lane >> 4) * 8]);
        const int chb = w * 64 + t * 16 + (lane >> 4) * 4;   // channels this lane OUTPUTS
        as4[t] = *reinterpret_cast<const float4*>(&aS[chb]);
        ad4[t] = *reinterpret_cast<const float4*>(&aD[chb]);
    }

    const int ntiles = N_NODES / 32;
    for (int tile = blockIdx.x; tile < ntiles; tile += gridDim.x) {
        const int n0 = tile * 32;
        __syncthreads();
        for (int idx = tid; idx < 32 * K; idx += 256) {
            int r = idx / K, k = idx - r * K;
            xs[r * KP + k] = (k < IN_DIM) ? f2bf(xin[(size_t)(n0 + r) * IN_DIM + k])
                                          : (unsigned short)0;
        }
        __syncthreads();

#pragma unroll
        for (int m = 0; m < 2; ++m) {
            bf16x8 xfrag[KS];
#pragma unroll
            for (int s = 0; s < KS; ++s)
                xfrag[s] = *reinterpret_cast<const bf16x8*>(
                    &xs[(m * 16 + (lane & 15)) * KP + s * 32 + (lane >> 4) * 8]);

            const int node = n0 + m * 16 + (lane & 15);
            float sv = 0.f, dv = 0.f;
#pragma unroll
            for (int t = 0; t < 4; ++t) {
                f32x4 a = {0.f, 0.f, 0.f, 0.f};
#pragma unroll
                for (int s = 0; s < KS; ++s)
                    a = __builtin_amdgcn_mfma_f32_16x16x32_bf16(wfrag[t][s], xfrag[s], a, 0, 0, 0);
                const int chb = w * 64 + t * 16 + (lane >> 4) * 4;
                *reinterpret_cast<unsigned*>(&hfull[(size_t)node * 256 + chb]) =
                    fp8pack4(a[0], a[1], a[2], a[3]);
                sv += a[0] * as4[t].x + a[1] * as4[t].y + a[2] * as4[t].z + a[3] * as4[t].w;
                dv += a[0] * ad4[t].x + a[1] * ad4[t].y + a[2] * ad4[t].z + a[3] * ad4[t].w;
            }
            sv += __shfl_xor(sv, 16, 64); dv += __shfl_xor(dv, 16, 64);
            sv += __shfl_xor(sv, 32, 64); dv += __shfl_xor(dv, 32, 64);
            if (lane < 16) {
                sArr[node * 4 + w] = sv;
                dArr[node * 4 + w] = dv;
            }
        }
    }
}

// ---------------- fused once-per-call setup: padded CSR + seg bounds + gsum=0 -------
__global__ void setup_csr(const int* __restrict__ ei, const int* __restrict__ batch,
                          int* __restrict__ cnt, int* __restrict__ csrc,
                          int* __restrict__ start, float* __restrict__ gsum) {
    int gid = blockIdx.x * 256 + threadIdx.x;
    if (gid == 0) *gsum = 0.f;
    if (gid < N_EDGES) {
        int src = ei[gid], dst = ei[N_EDGES + gid];
        int slot = atomicAdd(&cnt[dst], 1);
        csrc[(size_t)dst * PADDEG + slot] = src;
    }
    if (gid < N_NODES) {
        int b1 = batch[gid];
        int b0 = (gid == 0) ? -1 : batch[gid - 1];
        for (int b = b0 + 1; b <= b1; ++b) start[b] = gid;
        if (gid == N_NODES - 1)
            for (int b = b1 + 1; b <= N_B; ++b) start[b] = N_NODES;
    }
}

// ---------------- fused alpha + gather: FOUR dst nodes per wave, fp8 hfull ----------
template<bool POOL>
__launch_bounds__(256)
__global__ void gat_gather(const int* __restrict__ cnt, const int* __restrict__ csrc,
                           const float* __restrict__ sArr, const float* __restrict__ dArr,
                           const unsigned char* __restrict__ hfull, // [N,256] fp8
                           const float* __restrict__ bias,
                           const float* __restrict__ poolW, const float* __restrict__ poolB,
                           float* __restrict__ xout,
                           float* __restrict__ logit, float* __restrict__ pmax) {
    constexpr int CAP = 32;
    __shared__ float qbuf[4][4][CAP * 4];
    __shared__ int   sbuf[4][4][CAP];
    __shared__ float red[16];

    const int wid = threadIdx.x >> 6;
    const int lane = threadIdx.x & 63;
    const int nl = lane >> 4;            // node within wave (0..3)
    const int sub = lane & 15;
    const int n = blockIdx.x * 16 + wid * 4 + nl;

    const int jb = n * PADDEG;
    const int deg = cnt[n];

    // ---- phase 1: q = exp(lrelu(s+d)), Z accumulate ----
    const int hh = sub & 3;
    const int slot = sub >> 2;           // 0..3
    const float dv = dArr[n * 4 + hh];
    const float qself = expf(lrelu(sArr[n * 4 + hh] + dv));
    float zp = 0.f;

    for (int base = 0; base < deg; base += 4) {
        int s = base + slot;
        if (s < deg) {
            int src = csrc[jb + s];
            float q = expf(lrelu(sArr[src * 4 + hh] + dv));
            if (s < CAP) {
                qbuf[wid][nl][s * 4 + hh] = q;
                if (hh == 0) sbuf[wid][nl][s] = src;
            }
            zp += q;
        }
    }
    zp += __shfl_xor(zp, 4, 64);
    zp += __shfl_xor(zp, 8, 64);
    const float inv = 0.25f / (zp + qself);
    __threadfence_block();

    // ---- phase 2: gather, 16 channels/lane = ONE uint4 (16 fp8) per edge ----
    const int h = sub >> 2;              // head of this lane's channels
    const int c16 = sub * 16;            // byte offset into 256B row
    const int bl = (lane & 48) + h;      // lane in same node with hh==h, slot==0
    const float inv_g = __shfl(inv, bl, 64);
    const float qs_g  = __shfl(qself, bl, 64);
    const int dcap = deg < CAP ? deg : CAP;

#define LOADF8(S) (*reinterpret_cast<const uint4*>(&hfull[(size_t)(unsigned)(S) * 256 + c16]))
#define UNPK16(A, Q, U) { \
    f32x2 v_; \
    v_ = fp8pair<false>((U).x); A[0]  = fmaf((Q), v_.x, A[0]);  A[1]  = fmaf((Q), v_.y, A[1]); \
    v_ = fp8pair<true >((U).x); A[2]  = fmaf((Q), v_.x, A[2]);  A[3]  = fmaf((Q), v_.y, A[3]); \
    v_ = fp8pair<false>((U).y); A[4]  = fmaf((Q), v_.x, A[4]);  A[5]  = fmaf((Q), v_.y, A[5]); \
    v_ = fp8pair<true >((U).y); A[6]  = fmaf((Q), v_.x, A[6]);  A[7]  = fmaf((Q), v_.y, A[7]); \
    v_ = fp8pair<false>((U).z); A[8]  = fmaf((Q), v_.x, A[8]);  A[9]  = fmaf((Q), v_.y, A[9]); \
    v_ = fp8pair<true >((U).z); A[10] = fmaf((Q), v_.x, A[10]); A[11] = fmaf((Q), v_.y, A[11]); \
    v_ = fp8pair<false>((U).w); A[12] = fmaf((Q), v_.x, A[12]); A[13] = fmaf((Q), v_.y, A[13]); \
    v_ = fp8pair<true >((U).w); A[14] = fmaf((Q), v_.x, A[14]); A[15] = fmaf((Q), v_.y, A[15]); }

    float acc[16] = {0, 0, 0, 0, 0, 0, 0, 0, 0, 0, 0, 0, 0, 0, 0, 0};
    {
        uint4 us = LOADF8(n);
        UNPK16(acc, qs_g, us);
    }
    int s = 0;
    for (; s + 1 < dcap; s += 2) {
        int s0 = sbuf[wid][nl][s], s1 = sbuf[wid][nl][s + 1];
        float q0 = qbuf[wid][nl][s * 4 + h];
        float q1 = qbuf[wid][nl][(s + 1) * 4 + h];
        uint4 u0 = LOADF8(s0);
        uint4 u1 = LOADF8(s1);
        UNPK16(acc, q0, u0);
        UNPK16(acc, q1, u1);
    }
    if (s < dcap) {
        int s0 = sbuf[wid][nl][s];
        float q0 = qbuf[wid][nl][s * 4 + h];
        uint4 u0 = LOADF8(s0);
        UNPK16(acc, q0, u0);
    }
    if (deg > CAP) {   // overflow fallback (never taken for this input): recompute q
        const float dvh = dArr[n * 4 + h];
        for (int t = CAP; t < deg; ++t) {
            int st = csrc[jb + t];
            float q = expf(lrelu(sArr[st * 4 + h] + dvh));
            uint4 ua = LOADF8(st);
            UNPK16(acc, q, ua);
        }
    }
#undef UNPK16
#undef LOADF8

    // normalize by this head's 1/Z, then head-mean across the 4 head groups (bits 2,3)
#pragma unroll
    for (int j = 0; j < 16; ++j) acc[j] *= inv_g;
#pragma unroll
    for (int j = 0; j < 16; ++j) {
        acc[j] += __shfl_xor(acc[j], 4, 64);
        acc[j] += __shfl_xor(acc[j], 8, 64);
    }

    // lane (h, q=sub&3) finishes 4 contiguous channels cc = q*16 + h*4
    const int qq = sub & 3;
    const int cc = qq * 16 + h * 4;
    float v0 = (h == 0) ? acc[0] : (h == 1) ? acc[4] : (h == 2) ? acc[8]  : acc[12];
    float v1 = (h == 0) ? acc[1] : (h == 1) ? acc[5] : (h == 2) ? acc[9]  : acc[13];
    float v2 = (h == 0) ? acc[2] : (h == 1) ? acc[6] : (h == 2) ? acc[10] : acc[14];
    float v3 = (h == 0) ? acc[3] : (h == 1) ? acc[7] : (h == 2) ? acc[11] : acc[15];
    const float4 b4 = *reinterpret_cast<const float4*>(&bias[cc]);
    float4 o4;
    o4.x = gelu_exact(v0 + b4.x);
    o4.y = gelu_exact(v1 + b4.y);
    o4.z = gelu_exact(v2 + b4.z);
    o4.w = gelu_exact(v3 + b4.w);
    *reinterpret_cast<float4*>(&xout[(size_t)n * 64 + cc]) = o4;

    if (POOL) {
        const float4 pw = *reinterpret_cast<const float4*>(&poolW[cc]);
        float p = o4.x * pw.x + o4.y * pw.y + o4.z * pw.z + o4.w * pw.w;
#pragma unroll
        for (int of = 1; of < 16; of <<= 1) p += __shfl_xor(p, of, 64);
        float lg = p + poolB[0];
        if (sub == 0) {
            logit[n] = lg;
            red[wid * 4 + nl] = lg;
        }
        __syncthreads();
        if (threadIdx.x == 0) {
            float mm = red[0];
#pragma unroll
            for (int i = 1; i < 16; ++i) mm = fmaxf(mm, red[i]);
            pmax[blockIdx.x] = mm;
        }
    }
}

// ---------------- per-graph pooling with inline global-max over pmax ----------------
__global__ void pool_graph(const float* __restrict__ h3,
                           const float* __restrict__ logit,
                           const float* __restrict__ pmax,
                           const int* __restrict__ start,
                           float* __restrict__ pooled,
                           float* __restrict__ gsum) {
    __shared__ float gred[256];
    __shared__ float sacc[4][64];
    __shared__ float sw[4];
    int b = blockIdx.x;
    int lane = threadIdx.x & 63, wid = threadIdx.x >> 6;

    float m = -INFINITY;
    for (int i = threadIdx.x; i < NPMAX; i += 256) m = fmaxf(m, pmax[i]);
    gred[threadIdx.x] = m;
    __syncthreads();
    for (int s = 128; s > 0; s >>= 1) {
        if (threadIdx.x < s) gred[threadIdx.x] = fmaxf(gred[threadIdx.x], gred[threadIdx.x + s]);
        __syncthreads();
    }
    const float M = gred[0];

    int s = start[b], e = start[b + 1];
    float acc = 0.f, wsum = 0.f;
    for (int n = s + wid; n < e; n += 4) {
        float w = expf(logit[n] - M);
        acc += h3[(size_t)n * 64 + lane] * w;
        if (lane == 0) wsum += w;
    }
    sacc[wid][lane] = acc;
    if (lane == 0) sw[wid] = wsum;
    __syncthreads();
    if (wid == 0) {
        pooled[(size_t)b * 64 + lane] = sacc[0][lane] + sacc[1][lane] + sacc[2][lane] + sacc[3][lane];
        if (lane == 0) atomicAdd(gsum, sw[0] + sw[1] + sw[2] + sw[3]);
    }
}

// ---------------- head1 split-K part: 8 graphs/block --------------------------------
constexpr int GB1  = 8;
constexpr int KSEG = 372;   // 744 = 2 segments of 372 (93 aligned float4)

__launch_bounds__(256, 4)
__global__ void head1_part(const float* __restrict__ pooled, const float* __restrict__ gsum,
                           const float* __restrict__ rnafm, const float* __restrict__ hand,
                           const float* __restrict__ e1W,
                           float* __restrict__ part) {   // [2][N_B][256]
    __shared__ __align__(16) float fused[GB1][KSEG + 4];
    const int bq = blockIdx.x >> 1;
    const int ks = blockIdx.x & 1;
    const int g0 = bq * GB1;
    const int k0 = ks * KSEG;
    const int tid = threadIdx.x;
    const float inv = 1.0f / *gsum;

    for (int idx = tid; idx < GB1 * KSEG; idx += 256) {
        int g = idx / KSEG, kk = idx - g * KSEG;
        int k = kk + k0;
        int b = g0 + g;
        float v;
        if (k < 64)       v = pooled[(size_t)b * 64 + k] * inv;
        else if (k < 704) v = rnafm[(size_t)b * 640 + (k - 64)];
        else              v = hand[(size_t)b * 40 + (k - 704)];
        fused[g][kk] = v;
    }
    __syncthreads();

    const float* wr = e1W + (size_t)tid * 744 + k0;
    float a0 = 0.f, a1 = 0.f, a2 = 0.f, a3 = 0.f;
    float a4 = 0.f, a5 = 0.f, a6 = 0.f, a7 = 0.f;
    for (int q = 0; q < KSEG / 4; ++q) {
        float4 w4 = *reinterpret_cast<const float4*>(wr + q * 4);
        float4 f0 = *reinterpret_cast<const float4*>(&fused[0][q * 4]);
        float4 f1 = *reinterpret_cast<const float4*>(&fused[1][q * 4]);
        float4 f2 = *reinterpret_cast<const float4*>(&fused[2][q * 4]);
        float4 f3 = *reinterpret_cast<const float4*>(&fused[3][q * 4]);
        float4 f4 = *reinterpret_cast<const float4*>(&fused[4][q * 4]);
        float4 f5 = *reinterpret_cast<const float4*>(&fused[5][q * 4]);
        float4 f6 = *reinterpret_cast<const float4*>(&fused[6][q * 4]);
        float4 f7 = *reinterpret_cast<const float4*>(&fused[7][q * 4]);
        a0 += f0.x * w4.x + f0.y * w4.y + f0.z * w4.z + f0.w * w4.w;
        a1 += f1.x * w4.x + f1.y * w4.y + f1.z * w4.z + f1.w * w4.w;
        a2 += f2.x * w4.x + f2.y * w4.y + f2.z * w4.z + f2.w * w4.w;
        a3 += f3.x * w4.x + f3.y * w4.y + f3.z * w4.z + f3.w * w4.w;
        a4 += f4.x * w4.x + f4.y * w4.y + f4.z * w4.z + f4.w * w4.w;
        a5 += f5.x * w4.x + f5.y * w4.y + f5.z * w4.z + f5.w * w4.w;
        a6 += f6.x * w4.x + f6.y * w4.y + f6.z * w4.z + f6.w * w4.w;
        a7 += f7.x * w4.x + f7.y * w4.y + f7.z * w4.z + f7.w * w4.w;
    }
    float* po = part + ((size_t)ks * N_B + g0) * 256 + tid;
    po[0 * 256] = a0; po[1 * 256] = a1; po[2 * 256] = a2; po[3 * 256] = a3;
    po[4 * 256] = a4; po[5 * 256] = a5; po[6 * 256] = a6; po[7 * 256] = a7;
}

// ---------------- fused head tail: LN + e2 + {binary, per, cls}, 4 graphs/block ------
__launch_bounds__(256, 2)
__global__ void head_fused(const float* __restrict__ part,
                           const float* __restrict__ e1b,
                           const float* __restrict__ lng, const float* __restrict__ lnb,
                           const float* __restrict__ e2W, const float* __restrict__ e2b,
                           const float* __restrict__ binW, const float* __restrict__ binB,
                           const float* __restrict__ ad1W, const float* __restrict__ ad1b,
                           const float* __restrict__ ad2W, const float* __restrict__ ad2b,
                           const float* __restrict__ c1W, const float* __restrict__ c1b,
                           const float* __restrict__ c2W, const float* __restrict__ c2b,
                           float* __restrict__ out) {
    __shared__ float zr[4][256];
    __shared__ float red1[4][4], red2[4][4];
    __shared__ float sv[4][128];
    __shared__ float t64[4][64];
    __shared__ float h1s[4][5][32];
    __shared__ float binred[4][32];
    const int b0 = blockIdx.x * 4;
    const int tid = threadIdx.x;
    const int lane = tid & 63, wid = tid >> 6;

    const float eb = e1b[tid];
    float g0 = gelu_exact(part[(size_t)(b0 + 0) * 256 + tid] + part[((size_t)N_B + b0 + 0) * 256 + tid] + eb);
    float g1 = gelu_exact(part[(size_t)(b0 + 1) * 256 + tid] + part[((size_t)N_B + b0 + 1) * 256 + tid] + eb);
    float g2 = gelu_exact(part[(size_t)(b0 + 2) * 256 + tid] + part[((size_t)N_B + b0 + 2) * 256 + tid] + eb);
    float g3 = gelu_exact(part[(size_t)(b0 + 3) * 256 + tid] + part[((size_t)N_B + b0 + 3) * 256 + tid] + eb);

    float s10 = g0, s11 = g1, s12 = g2, s13 = g3;
    float s20 = g0 * g0, s21 = g1 * g1, s22 = g2 * g2, s23 = g3 * g3;
#pragma unroll
    for (int o = 1; o < 64; o <<= 1) {
        s10 += __shfl_xor(s10, o, 64); s11 += __shfl_xor(s11, o, 64);
        s12 += __shfl_xor(s12, o, 64); s13 += __shfl_xor(s13, o, 64);
        s20 += __shfl_xor(s20, o, 64); s21 += __shfl_xor(s21, o, 64);
        s22 += __shfl_xor(s22, o, 64); s23 += __shfl_xor(s23, o, 64);
    }
    if (lane == 0) {
        red1[wid][0] = s10; red1[wid][1] = s11; red1[wid][2] = s12; red1[wid][3] = s13;
        red2[wid][0] = s20; red2[wid][1] = s21; red2[wid][2] = s22; red2[wid][3] = s23;
    }
    __syncthreads();

    const float gN = lng[tid], bN = lnb[tid];
#pragma unroll
    for (int bb = 0; bb < 4; ++bb) {
        float s1 = red1[0][bb] + red1[1][bb] + red1[2][bb] + red1[3][bb];
        float s2 = red2[0][bb] + red2[1][bb] + red2[2][bb] + red2[3][bb];
        float mu  = s1 * (1.0f / 256.0f);
        float var = s2 * (1.0f / 256.0f) - mu * mu;
        float g = (bb == 0) ? g0 : (bb == 1) ? g1 : (bb == 2) ? g2 : g3;
        zr[bb][tid] = (g - mu) * rsqrtf(var + 1e-5f) * gN + bN;
    }
    __syncthreads();

    {
        const int ch = tid & 127, gp = tid >> 7;   // gp covers graphs gp*2, gp*2+1
        const float* wr = e2W + (size_t)ch * 256;
        const float e2bb = e2b[ch];
        float a0 = e2bb, a1 = e2bb;
        for (int k = 0; k < 256; k += 4) {
            float4 w4 = *reinterpret_cast<const float4*>(wr + k);
            float4 f0 = *reinterpret_cast<const float4*>(&zr[gp * 2][k]);
            float4 f1 = *reinterpret_cast<const float4*>(&zr[gp * 2 + 1][k]);
            a0 += f0.x * w4.x + f0.y * w4.y + f0.z * w4.z + f0.w * w4.w;
            a1 += f1.x * w4.x + f1.y * w4.y + f1.z * w4.z + f1.w * w4.w;
        }
        sv[gp * 2][ch]     = gelu_exact(a0);
        sv[gp * 2 + 1][ch] = gelu_exact(a1);
    }
    __syncthreads();

    for (int idx = tid; idx < 256 + 640; idx += 256) {
        if (idx < 256) {
            int g = idx >> 6, ch = idx & 63;
            float a = c1b[ch];
            const float* wr = c1W + (size_t)ch * 128;
            for (int k = 0; k < 128; ++k) a += sv[g][k] * wr[k];
            t64[g][ch] = gelu_exact(a);
        } else {
            int j = idx - 256;
            int g = j / 160, r = j - g * 160;
            int e = r >> 5, hh = r & 31;
            float a = ad1b[e * 32 + hh];
            const float* wr = ad1W + (size_t)(e * 32 + hh) * 128;
            for (int k = 0; k < 128; ++k) a += sv[g][k] * wr[k];
            h1s[g][e][hh] = gelu_exact(a);
        }
    }
    if (tid < 128) {
        int g = tid >> 5, r = tid & 31;
        float a = 0.f;
#pragma unroll
        for (int k = 0; k < 4; ++k) a += sv[g][r * 4 + k] * binW[r * 4 + k];
        binred[g][r] = a;
    }
    __syncthreads();

    if (tid < 24) {            // cls: 6 x 4 graphs
        int g = tid / 6, c = tid - g * 6;
        float a = c2b[c];
        const float* wr = c2W + (size_t)c * 64;
        for (int k = 0; k < 64; ++k) a += t64[g][k] * wr[k];
        out[4800 + (size_t)(b0 + g) * 6 + c] = a;
    }
    if (tid >= 32 && tid < 52) {  // per: 5 x 4 graphs
        int j = tid - 32;
        int g = j / 5, e = j - g * 5;
        float a = ad2b[e];
        const float* wr = ad2W + (size_t)e * 32;
        for (int k = 0; k < 32; ++k) a += h1s[g][e][k] * wr[k];
        out[800 + (size_t)e * 800 + (b0 + g)] = a;
    }
    if (tid >= 64 && tid < 68) {  // binary: 4 graphs
        int g = tid - 64;
        float a = binB[0];
        for (int r = 0; r < 32; ++r) a += binred[g][r];
        out[b0 + g] = a;
    }
}

extern "C" void kernel_launch(void* const* d_in, const int* in_sizes, int n_in,
                              void* d_out, int out_size, void* d_ws, size_t ws_size,
                              hipStream_t stream) {
    const float* x       = (const float*)d_in[0];
    const int*   ei      = (const int*)d_in[1];
    const int*   batch   = (const int*)d_in[2];
    const float* rnafm   = (const float*)d_in[3];
    const float* hand    = (const float*)d_in[4];
    const float* gW[3]  = {(const float*)d_in[5],  (const float*)d_in[9],  (const float*)d_in[13]};
    const float* gAs[3] = {(const float*)d_in[6],  (const float*)d_in[10], (const float*)d_in[14]};
    const float* gAd[3] = {(const float*)d_in[7],  (const float*)d_in[11], (const float*)d_in[15]};
    const float* gB[3]  = {(const float*)d_in[8],  (const float*)d_in[12], (const float*)d_in[16]};
    const float* poolW = (const float*)d_in[17];
    const float* poolB = (const float*)d_in[18];
    const float* e1W = (const float*)d_in[19]; const float* e1b = (const float*)d_in[20];
    const float* lng = (const float*)d_in[21]; const float* lnb = (const float*)d_in[22];
    const float* e2W = (const float*)d_in[23]; const float* e2b = (const float*)d_in[24];
    const float* binW = (const float*)d_in[25]; const float* binB = (const float*)d_in[26];
    const float* ad1W = (const float*)d_in[27]; const float* ad1b = (const float*)d_in[28];
    const float* ad2W = (const float*)d_in[29]; const float* ad2b = (const float*)d_in[30];
    const float* c1W = (const float*)d_in[31]; const float* c1b = (const float*)d_in[32];
    const float* c2W = (const float*)d_in[33]; const float* c2b = (const float*)d_in[34];
    float* out = (float*)d_out;

    float* ws = (float*)d_ws;
    size_t off = 0;
    unsigned char* hfull = (unsigned char*)(ws + off); off += (size_t)N_NODES * 64; // fp8 [N,256]
    float* xcur   = ws + off; off += (size_t)N_NODES * 64;
    float* sArr   = ws + off; off += (size_t)N_NODES * 4;
    float* dArr   = ws + off; off += (size_t)N_NODES * 4;
    int*   cnt    = (int*)(ws + off); off += N_NODES;
    int*   csrc   = (int*)(ws + off); off += (size_t)N_NODES * PADDEG;
    float* logit  = ws + off; off += N_NODES;
    float* pmax   = ws + off; off += NPMAX;
    float* pooled = ws + off; off += (size_t)N_B * 64;
    float* part   = ws + off; off += (size_t)2 * N_B * 256;
    int*   start  = (int*)(ws + off); off += (N_B + 1);
    float* gsum   = ws + off; off += 1;

    // ---- one-time per call: padded CSR + segment bounds + gsum=0 (fused) ----
    hipMemsetAsync(cnt, 0, N_NODES * sizeof(int), stream);
    setup_csr<<<(N_EDGES + 255) / 256, 256, 0, stream>>>(ei, batch, cnt, csrc, start, gsum);

    // ---- 3 GAT layers ----
    for (int layer = 0; layer < 3; ++layer) {
        const float* xin = (layer == 0) ? x : xcur;
        if (layer == 0)
            gat_transform<21><<<512, 256, 0, stream>>>(xin, gW[0], gAs[0], gAd[0], hfull, sArr, dArr);
        else
            gat_transform<64><<<512, 256, 0, stream>>>(xin, gW[layer], gAs[layer], gAd[layer], hfull, sArr, dArr);
        if (layer < 2)
            gat_gather<false><<<N_NODES / 16, 256, 0, stream>>>(cnt, csrc, sArr, dArr, hfull,
                                                                gB[layer], nullptr, nullptr,
                                                                xcur, nullptr, nullptr);
        else
            gat_gather<true><<<N_NODES / 16, 256, 0, stream>>>(cnt, csrc, sArr, dArr, hfull,
                                                               gB[2], poolW, poolB,
                                                               xcur, logit, pmax);
    }

    // ---- pooling + heads ----
    pool_graph<<<N_B, 256, 0, stream>>>(xcur, logit, pmax, start, pooled, gsum);

    head1_part<<<(N_B / GB1) * 2, 256, 0, stream>>>(pooled, gsum, rnafm, hand, e1W, part);
    head_fused<<<N_B / 4, 256, 0, stream>>>(part, e1b, lng, lnb, e2W, e2b,
                                            binW, binB, ad1W, ad1b, ad2W, ad2b,
                                            c1W, c1b, c2W, c2b, out);
}

// Round 22
// 300.393 us; speedup vs baseline: 1.1813x; 1.0018x over previous
//
#include <hip/hip_runtime.h>
#include <hip/hip_bf16.h>
#include <math.h>

constexpr int N_NODES = 80000;
constexpr int N_EDGES = 480000;
constexpr int N_B     = 800;
constexpr int PADDEG  = 64;     // padded CSR row storage
constexpr int NPMAX   = N_NODES / 16;   // 5000 pmax entries

typedef __attribute__((ext_vector_type(8))) short bf16x8;
typedef __attribute__((ext_vector_type(4))) float f32x4;
typedef __attribute__((ext_vector_type(2))) float f32x2;

#if defined(__HIP_DEVICE_COMPILE__) && defined(__has_builtin)
#if __has_builtin(__builtin_amdgcn_cvt_pk_f32_fp8) && __has_builtin(__builtin_amdgcn_cvt_pk_fp8_f32)
#define HW_FP8 1
#endif
#endif

__device__ __forceinline__ float gelu_exact(float x) {
    return 0.5f * x * (1.0f + erff(x * 0.70710678118654752f));
}
__device__ __forceinline__ float lrelu(float v) {
    return v > 0.f ? v : 0.2f * v;
}
// fp32 <-> bf16 (RNE)
__device__ __forceinline__ unsigned short f2bf(float f) {
    unsigned u = __float_as_uint(f);
    unsigned r = u + 0x7FFFu + ((u >> 16) & 1u);
    return (unsigned short)(r >> 16);
}

// ---- fp8 e4m3 helpers: HW cvt on gfx950; pure-bit software fallback (host-safe) ----
__device__ __forceinline__ float dec8_sw(unsigned b) {
    unsigned s = (b >> 7) & 1u, e = (b >> 3) & 15u, m = b & 7u;
    float v = e ? __uint_as_float(((e + 120u) << 23) | (m << 20))
                : (float)m * 0.001953125f;           // subnormal: m * 2^-9
    return s ? -v : v;
}
__device__ __forceinline__ unsigned enc8_sw(float x) {
    unsigned u = __float_as_uint(x);
    unsigned s = u >> 31;
    u &= 0x7FFFFFFFu;
    if (__uint_as_float(u) > 448.f) u = __float_as_uint(448.f);
    unsigned byte;
    if (__uint_as_float(u) < 0.015625f) {            // < 2^-6: e4m3 subnormal
        int q = (int)rintf(__uint_as_float(u) * 512.f);   // units of 2^-9
        if (q > 7) q = 7;
        byte = (unsigned)q;
    } else {
        unsigned r = u + 0x7FFFFu + ((u >> 20) & 1u);    // RNE 23->3 mantissa bits
        int e = (int)(r >> 23) - 127;
        unsigned m = (r >> 20) & 7u;
        if (e > 8) { e = 8; m = 7u; }                    // clamp to 448
        byte = ((unsigned)(e + 7) << 3) | m;
    }
    return (s << 7) | byte;
}

template<bool HI>
__device__ __forceinline__ f32x2 fp8pair(unsigned u) {
#ifdef HW_FP8
    return __builtin_amdgcn_cvt_pk_f32_fp8((int)u, HI);
#else
    f32x2 v;
    v.x = dec8_sw((u >> (HI ? 16 : 0)) & 0xFFu);
    v.y = dec8_sw((u >> (HI ? 24 : 8)) & 0xFFu);
    return v;
#endif
}
__device__ __forceinline__ unsigned fp8pack4(float a0, float a1, float a2, float a3) {
#ifdef HW_FP8
    int p = __builtin_amdgcn_cvt_pk_fp8_f32(a0, a1, 0, false);
    p = __builtin_amdgcn_cvt_pk_fp8_f32(a2, a3, p, true);
    return (unsigned)p;
#else
    return enc8_sw(a0) | (enc8_sw(a1) << 8) | (enc8_sw(a2) << 16) | (enc8_sw(a3) << 24);
#endif
}

// ---------------- GAT node transform: MFMA bf16, D = W·X^T, fp8 hfull out -----------
template<int IN_DIM>
__launch_bounds__(256, 2)
__global__ void gat_transform(const float* __restrict__ xin,
                              const float* __restrict__ W,    // [256, IN_DIM] row-major
                              const float* __restrict__ aS,   // [256]
                              const float* __restrict__ aD,
                              unsigned char* __restrict__ hfull,   // [N,256] fp8 e4m3
                              float* __restrict__ sArr,       // [N,4]
                              float* __restrict__ dArr) {
    constexpr int K  = (IN_DIM + 31) & ~31;     // 32 or 64
    constexpr int KS = K / 32;                  // k-steps
    constexpr int KP = K + 8;                   // +8 bf16 row pad
    __shared__ __align__(16) unsigned short Wb[256 * KP];
    __shared__ __align__(16) unsigned short xs[32 * KP];

    const int tid = threadIdx.x;
    const int lane = tid & 63, w = tid >> 6;

    for (int idx = tid; idx < 256 * K; idx += 256) {
        int c = idx / K, k = idx - c * K;
        Wb[c * KP + k] = (k < IN_DIM) ? f2bf(W[c * IN_DIM + k]) : (unsigned short)0;
    }
    __syncthreads();

    bf16x8 wfrag[4][KS];
    float4 as4[4], ad4[4];
#pragma unroll
    for (int t = 0; t < 4; ++t) {
        const int ch = w * 64 + t * 16 + (lane & 15);
#pragma unroll
        for (int s = 0; s < KS; ++s)
            wfrag[t][s] = *reinterpret_cast<const bf16x8*>(&Wb[ch * KP + s * 32 + (lane >> 4) * 8]);
        const int chb = w * 64 + t * 16 + (lane >> 4) * 4;   // channels this lane OUTPUTS
        as4[t] = *reinterpret_cast<const float4*>(&aS[chb]);
        ad4[t] = *reinterpret_cast<const float4*>(&aD[chb]);
    }

    const int ntiles = N_NODES / 32;
    for (int tile = blockIdx.x; tile < ntiles; tile += gridDim.x) {
        const int n0 = tile * 32;
        __syncthreads();
        for (int idx = tid; idx < 32 * K; idx += 256) {
            int r = idx / K, k = idx - r * K;
            xs[r * KP + k] = (k < IN_DIM) ? f2bf(xin[(size_t)(n0 + r) * IN_DIM + k])
                                          : (unsigned short)0;
        }
        __syncthreads();

#pragma unroll
        for (int m = 0; m < 2; ++m) {
            bf16x8 xfrag[KS];
#pragma unroll
            for (int s = 0; s < KS; ++s)
                xfrag[s] = *reinterpret_cast<const bf16x8*>(
                    &xs[(m * 16 + (lane & 15)) * KP + s * 32 + (lane >> 4) * 8]);

            const int node = n0 + m * 16 + (lane & 15);
            float sv = 0.f, dv = 0.f;
#pragma unroll
            for (int t = 0; t < 4; ++t) {
                f32x4 a = {0.f, 0.f, 0.f, 0.f};
#pragma unroll
                for (int s = 0; s < KS; ++s)
                    a = __builtin_amdgcn_mfma_f32_16x16x32_bf16(wfrag[t][s], xfrag[s], a, 0, 0, 0);
                const int chb = w * 64 + t * 16 + (lane >> 4) * 4;
                *reinterpret_cast<unsigned*>(&hfull[(size_t)node * 256 + chb]) =
                    fp8pack4(a[0], a[1], a[2], a[3]);
                sv += a[0] * as4[t].x + a[1] * as4[t].y + a[2] * as4[t].z + a[3] * as4[t].w;
                dv += a[0] * ad4[t].x + a[1] * ad4[t].y + a[2] * ad4[t].z + a[3] * ad4[t].w;
            }
            sv += __shfl_xor(sv, 16, 64); dv += __shfl_xor(dv, 16, 64);
            sv += __shfl_xor(sv, 32, 64); dv += __shfl_xor(dv, 32, 64);
            if (lane < 16) {
                sArr[node * 4 + w] = sv;
                dArr[node * 4 + w] = dv;
            }
        }
    }
}

// ---------------- fused once-per-call setup: padded CSR + seg bounds + gsum=0 -------
__global__ void setup_csr(const int* __restrict__ ei, const int* __restrict__ batch,
                          int* __restrict__ cnt, int* __restrict__ csrc,
                          int* __restrict__ start, float* __restrict__ gsum) {
    int gid = blockIdx.x * 256 + threadIdx.x;
    if (gid == 0) *gsum = 0.f;
    if (gid < N_EDGES) {
        int src = ei[gid], dst = ei[N_EDGES + gid];
        int slot = atomicAdd(&cnt[dst], 1);
        csrc[(size_t)dst * PADDEG + slot] = src;
    }
    if (gid < N_NODES) {
        int b1 = batch[gid];
        int b0 = (gid == 0) ? -1 : batch[gid - 1];
        for (int b = b0 + 1; b <= b1; ++b) start[b] = gid;
        if (gid == N_NODES - 1)
            for (int b = b1 + 1; b <= N_B; ++b) start[b] = N_NODES;
    }
}

// ---------------- fused alpha + gather: FOUR dst nodes per wave, fp8 hfull ----------
template<bool POOL>
__launch_bounds__(256)
__global__ void gat_gather(const int* __restrict__ cnt, const int* __restrict__ csrc,
                           const float* __restrict__ sArr, const float* __restrict__ dArr,
                           const unsigned char* __restrict__ hfull, // [N,256] fp8
                           const float* __restrict__ bias,
                           const float* __restrict__ poolW, const float* __restrict__ poolB,
                           float* __restrict__ xout,
                           float* __restrict__ logit, float* __restrict__ pmax) {
    constexpr int CAP = 32;
    __shared__ float qbuf[4][4][CAP * 4];
    __shared__ int   sbuf[4][4][CAP];
    __shared__ float red[16];

    const int wid = threadIdx.x >> 6;
    const int lane = threadIdx.x & 63;
    const int nl = lane >> 4;            // node within wave (0..3)
    const int sub = lane & 15;
    const int n = blockIdx.x * 16 + wid * 4 + nl;

    const int jb = n * PADDEG;
    const int deg = cnt[n];

    // ---- phase 1: q = exp(lrelu(s+d)), Z accumulate ----
    const int hh = sub & 3;
    const int slot = sub >> 2;           // 0..3
    const float dv = dArr[n * 4 + hh];
    const float qself = expf(lrelu(sArr[n * 4 + hh] + dv));
    float zp = 0.f;

    for (int base = 0; base < deg; base += 4) {
        int s = base + slot;
        if (s < deg) {
            int src = csrc[jb + s];
            float q = expf(lrelu(sArr[src * 4 + hh] + dv));
            if (s < CAP) {
                qbuf[wid][nl][s * 4 + hh] = q;
                if (hh == 0) sbuf[wid][nl][s] = src;
            }
            zp += q;
        }
    }
    zp += __shfl_xor(zp, 4, 64);
    zp += __shfl_xor(zp, 8, 64);
    const float inv = 0.25f / (zp + qself);
    __threadfence_block();

    // ---- phase 2: gather, 16 channels/lane = ONE uint4 (16 fp8) per edge ----
    const int h = sub >> 2;              // head of this lane's channels
    const int c16 = sub * 16;            // byte offset into 256B row
    const int bl = (lane & 48) + h;      // lane in same node with hh==h, slot==0
    const float inv_g = __shfl(inv, bl, 64);
    const float qs_g  = __shfl(qself, bl, 64);
    const int dcap = deg < CAP ? deg : CAP;

#define LOADF8(S) (*reinterpret_cast<const uint4*>(&hfull[(size_t)(unsigned)(S) * 256 + c16]))
#define UNPK16(A, Q, U) { \
    f32x2 v_; \
    v_ = fp8pair<false>((U).x); A[0]  = fmaf((Q), v_.x, A[0]);  A[1]  = fmaf((Q), v_.y, A[1]); \
    v_ = fp8pair<true >((U).x); A[2]  = fmaf((Q), v_.x, A[2]);  A[3]  = fmaf((Q), v_.y, A[3]); \
    v_ = fp8pair<false>((U).y); A[4]  = fmaf((Q), v_.x, A[4]);  A[5]  = fmaf((Q), v_.y, A[5]); \
    v_ = fp8pair<true >((U).y); A[6]  = fmaf((Q), v_.x, A[6]);  A[7]  = fmaf((Q), v_.y, A[7]); \
    v_ = fp8pair<false>((U).z); A[8]  = fmaf((Q), v_.x, A[8]);  A[9]  = fmaf((Q), v_.y, A[9]); \
    v_ = fp8pair<true >((U).z); A[10] = fmaf((Q), v_.x, A[10]); A[11] = fmaf((Q), v_.y, A[11]); \
    v_ = fp8pair<false>((U).w); A[12] = fmaf((Q), v_.x, A[12]); A[13] = fmaf((Q), v_.y, A[13]); \
    v_ = fp8pair<true >((U).w); A[14] = fmaf((Q), v_.x, A[14]); A[15] = fmaf((Q), v_.y, A[15]); }

    float acc[16] = {0, 0, 0, 0, 0, 0, 0, 0, 0, 0, 0, 0, 0, 0, 0, 0};
    {
        uint4 us = LOADF8(n);
        UNPK16(acc, qs_g, us);
    }
    int s = 0;
    for (; s + 1 < dcap; s += 2) {
        int s0 = sbuf[wid][nl][s], s1 = sbuf[wid][nl][s + 1];
        float q0 = qbuf[wid][nl][s * 4 + h];
        float q1 = qbuf[wid][nl][(s + 1) * 4 + h];
        uint4 u0 = LOADF8(s0);
        uint4 u1 = LOADF8(s1);
        UNPK16(acc, q0, u0);
        UNPK16(acc, q1, u1);
    }
    if (s < dcap) {
        int s0 = sbuf[wid][nl][s];
        float q0 = qbuf[wid][nl][s * 4 + h];
        uint4 u0 = LOADF8(s0);
        UNPK16(acc, q0, u0);
    }
    if (deg > CAP) {   // overflow fallback (never taken for this input): recompute q
        const float dvh = dArr[n * 4 + h];
        for (int t = CAP; t < deg; ++t) {
            int st = csrc[jb + t];
            float q = expf(lrelu(sArr[st * 4 + h] + dvh));
            uint4 ua = LOADF8(st);
            UNPK16(acc, q, ua);
        }
    }
#undef UNPK16
#undef LOADF8

    // normalize by this head's 1/Z, then head-mean across the 4 head groups (bits 2,3)
#pragma unroll
    for (int j = 0; j < 16; ++j) acc[j] *= inv_g;
#pragma unroll
    for (int j = 0; j < 16; ++j) {
        acc[j] += __shfl_xor(acc[j], 4, 64);
        acc[j] += __shfl_xor(acc[j], 8, 64);
    }

    // lane (h, q=sub&3) finishes 4 contiguous channels cc = q*16 + h*4
    const int qq = sub & 3;
    const int cc = qq * 16 + h * 4;
    float v0 = (h == 0) ? acc[0] : (h == 1) ? acc[4] : (h == 2) ? acc[8]  : acc[12];
    float v1 = (h == 0) ? acc[1] : (h == 1) ? acc[5] : (h == 2) ? acc[9]  : acc[13];
    float v2 = (h == 0) ? acc[2] : (h == 1) ? acc[6] : (h == 2) ? acc[10] : acc[14];
    float v3 = (h == 0) ? acc[3] : (h == 1) ? acc[7] : (h == 2) ? acc[11] : acc[15];
    const float4 b4 = *reinterpret_cast<const float4*>(&bias[cc]);
    float4 o4;
    o4.x = gelu_exact(v0 + b4.x);
    o4.y = gelu_exact(v1 + b4.y);
    o4.z = gelu_exact(v2 + b4.z);
    o4.w = gelu_exact(v3 + b4.w);
    *reinterpret_cast<float4*>(&xout[(size_t)n * 64 + cc]) = o4;

    if (POOL) {
        const float4 pw = *reinterpret_cast<const float4*>(&poolW[cc]);
        float p = o4.x * pw.x + o4.y * pw.y + o4.z * pw.z + o4.w * pw.w;
#pragma unroll
        for (int of = 1; of < 16; of <<= 1) p += __shfl_xor(p, of, 64);
        float lg = p + poolB[0];
        if (sub == 0) {
            logit[n] = lg;
            red[wid * 4 + nl] = lg;
        }
        __syncthreads();
        if (threadIdx.x == 0) {
            float mm = red[0];
#pragma unroll
            for (int i = 1; i < 16; ++i) mm = fmaxf(mm, red[i]);
            pmax[blockIdx.x] = mm;
        }
    }
}

// ---------------- per-graph pooling with inline global-max over pmax ----------------
__global__ void pool_graph(const float* __restrict__ h3,
                           const float* __restrict__ logit,
                           const float* __restrict__ pmax,
                           const int* __restrict__ start,
                           float* __restrict__ pooled,
                           float* __restrict__ gsum) {
    __shared__ float gred[256];
    __shared__ float sacc[4][64];
    __shared__ float sw[4];
    int b = blockIdx.x;
    int lane = threadIdx.x & 63, wid = threadIdx.x >> 6;

    float m = -INFINITY;
    for (int i = threadIdx.x; i < NPMAX; i += 256) m = fmaxf(m, pmax[i]);
    gred[threadIdx.x] = m;
    __syncthreads();
    for (int s = 128; s > 0; s >>= 1) {
        if (threadIdx.x < s) gred[threadIdx.x] = fmaxf(gred[threadIdx.x], gred[threadIdx.x + s]);
        __syncthreads();
    }
    const float M = gred[0];

    int s = start[b], e = start[b + 1];
    float acc = 0.f, wsum = 0.f;
    for (int n = s + wid; n < e; n += 4) {
        float w = expf(logit[n] - M);
        acc += h3[(size_t)n * 64 + lane] * w;
        if (lane == 0) wsum += w;
    }
    sacc[wid][lane] = acc;
    if (lane == 0) sw[wid] = wsum;
    __syncthreads();
    if (wid == 0) {
        pooled[(size_t)b * 64 + lane] = sacc[0][lane] + sacc[1][lane] + sacc[2][lane] + sacc[3][lane];
        if (lane == 0) atomicAdd(gsum, sw[0] + sw[1] + sw[2] + sw[3]);
    }
}

// ---------------- head1 split-K part: 8 graphs/block --------------------------------
constexpr int GB1  = 8;
constexpr int KSEG = 372;   // 744 = 2 segments of 372 (93 aligned float4)

__launch_bounds__(256, 4)
__global__ void head1_part(const float* __restrict__ pooled, const float* __restrict__ gsum,
                           const float* __restrict__ rnafm, const float* __restrict__ hand,
                           const float* __restrict__ e1W,
                           float* __restrict__ part) {   // [2][N_B][256]
    __shared__ __align__(16) float fused[GB1][KSEG + 4];
    const int bq = blockIdx.x >> 1;
    const int ks = blockIdx.x & 1;
    const int g0 = bq * GB1;
    const int k0 = ks * KSEG;
    const int tid = threadIdx.x;
    const float inv = 1.0f / *gsum;

    for (int idx = tid; idx < GB1 * KSEG; idx += 256) {
        int g = idx / KSEG, kk = idx - g * KSEG;
        int k = kk + k0;
        int b = g0 + g;
        float v;
        if (k < 64)       v = pooled[(size_t)b * 64 + k] * inv;
        else if (k < 704) v = rnafm[(size_t)b * 640 + (k - 64)];
        else              v = hand[(size_t)b * 40 + (k - 704)];
        fused[g][kk] = v;
    }
    __syncthreads();

    const float* wr = e1W + (size_t)tid * 744 + k0;
    float a0 = 0.f, a1 = 0.f, a2 = 0.f, a3 = 0.f;
    float a4 = 0.f, a5 = 0.f, a6 = 0.f, a7 = 0.f;
    for (int q = 0; q < KSEG / 4; ++q) {
        float4 w4 = *reinterpret_cast<const float4*>(wr + q * 4);
        float4 f0 = *reinterpret_cast<const float4*>(&fused[0][q * 4]);
        float4 f1 = *reinterpret_cast<const float4*>(&fused[1][q * 4]);
        float4 f2 = *reinterpret_cast<const float4*>(&fused[2][q * 4]);
        float4 f3 = *reinterpret_cast<const float4*>(&fused[3][q * 4]);
        float4 f4 = *reinterpret_cast<const float4*>(&fused[4][q * 4]);
        float4 f5 = *reinterpret_cast<const float4*>(&fused[5][q * 4]);
        float4 f6 = *reinterpret_cast<const float4*>(&fused[6][q * 4]);
        float4 f7 = *reinterpret_cast<const float4*>(&fused[7][q * 4]);
        a0 += f0.x * w4.x + f0.y * w4.y + f0.z * w4.z + f0.w * w4.w;
        a1 += f1.x * w4.x + f1.y * w4.y + f1.z * w4.z + f1.w * w4.w;
        a2 += f2.x * w4.x + f2.y * w4.y + f2.z * w4.z + f2.w * w4.w;
        a3 += f3.x * w4.x + f3.y * w4.y + f3.z * w4.z + f3.w * w4.w;
        a4 += f4.x * w4.x + f4.y * w4.y + f4.z * w4.z + f4.w * w4.w;
        a5 += f5.x * w4.x + f5.y * w4.y + f5.z * w4.z + f5.w * w4.w;
        a6 += f6.x * w4.x + f6.y * w4.y + f6.z * w4.z + f6.w * w4.w;
        a7 += f7.x * w4.x + f7.y * w4.y + f7.z * w4.z + f7.w * w4.w;
    }
    float* po = part + ((size_t)ks * N_B + g0) * 256 + tid;
    po[0 * 256] = a0; po[1 * 256] = a1; po[2 * 256] = a2; po[3 * 256] = a3;
    po[4 * 256] = a4; po[5 * 256] = a5; po[6 * 256] = a6; po[7 * 256] = a7;
}

// ---------------- fused head tail: LN + e2 + {binary, per, cls}, 4 graphs/block ------
__launch_bounds__(256, 2)
__global__ void head_fused(const float* __restrict__ part,
                           const float* __restrict__ e1b,
                           const float* __restrict__ lng, const float* __restrict__ lnb,
                           const float* __restrict__ e2W, const float* __restrict__ e2b,
                           const float* __restrict__ binW, const float* __restrict__ binB,
                           const float* __restrict__ ad1W, const float* __restrict__ ad1b,
                           const float* __restrict__ ad2W, const float* __restrict__ ad2b,
                           const float* __restrict__ c1W, const float* __restrict__ c1b,
                           const float* __restrict__ c2W, const float* __restrict__ c2b,
                           float* __restrict__ out) {
    __shared__ float zr[4][256];
    __shared__ float red1[4][4], red2[4][4];
    __shared__ float sv[4][128];
    __shared__ float t64[4][64];
    __shared__ float h1s[4][5][32];
    __shared__ float binred[4][32];
    const int b0 = blockIdx.x * 4;
    const int tid = threadIdx.x;
    const int lane = tid & 63, wid = tid >> 6;

    const float eb = e1b[tid];
    float g0 = gelu_exact(part[(size_t)(b0 + 0) * 256 + tid] + part[((size_t)N_B + b0 + 0) * 256 + tid] + eb);
    float g1 = gelu_exact(part[(size_t)(b0 + 1) * 256 + tid] + part[((size_t)N_B + b0 + 1) * 256 + tid] + eb);
    float g2 = gelu_exact(part[(size_t)(b0 + 2) * 256 + tid] + part[((size_t)N_B + b0 + 2) * 256 + tid] + eb);
    float g3 = gelu_exact(part[(size_t)(b0 + 3) * 256 + tid] + part[((size_t)N_B + b0 + 3) * 256 + tid] + eb);

    float s10 = g0, s11 = g1, s12 = g2, s13 = g3;
    float s20 = g0 * g0, s21 = g1 * g1, s22 = g2 * g2, s23 = g3 * g3;
#pragma unroll
    for (int o = 1; o < 64; o <<= 1) {
        s10 += __shfl_xor(s10, o, 64); s11 += __shfl_xor(s11, o, 64);
        s12 += __shfl_xor(s12, o, 64); s13 += __shfl_xor(s13, o, 64);
        s20 += __shfl_xor(s20, o, 64); s21 += __shfl_xor(s21, o, 64);
        s22 += __shfl_xor(s22, o, 64); s23 += __shfl_xor(s23, o, 64);
    }
    if (lane == 0) {
        red1[wid][0] = s10; red1[wid][1] = s11; red1[wid][2] = s12; red1[wid][3] = s13;
        red2[wid][0] = s20; red2[wid][1] = s21; red2[wid][2] = s22; red2[wid][3] = s23;
    }
    __syncthreads();

    const float gN = lng[tid], bN = lnb[tid];
#pragma unroll
    for (int bb = 0; bb < 4; ++bb) {
        float s1 = red1[0][bb] + red1[1][bb] + red1[2][bb] + red1[3][bb];
        float s2 = red2[0][bb] + red2[1][bb] + red2[2][bb] + red2[3][bb];
        float mu  = s1 * (1.0f / 256.0f);
        float var = s2 * (1.0f / 256.0f) - mu * mu;
        float g = (bb == 0) ? g0 : (bb == 1) ? g1 : (bb == 2) ? g2 : g3;
        zr[bb][tid] = (g - mu) * rsqrtf(var + 1e-5f) * gN + bN;
    }
    __syncthreads();

    {
        const int ch = tid & 127, gp = tid >> 7;   // gp covers graphs gp*2, gp*2+1
        const float* wr = e2W + (size_t)ch * 256;
        const float e2bb = e2b[ch];
        float a0 = e2bb, a1 = e2bb;
        for (int k = 0; k < 256; k += 4) {
            float4 w4 = *reinterpret_cast<const float4*>(wr + k);
            float4 f0 = *reinterpret_cast<const float4*>(&zr[gp * 2][k]);
            float4 f1 = *reinterpret_cast<const float4*>(&zr[gp * 2 + 1][k]);
            a0 += f0.x * w4.x + f0.y * w4.y + f0.z * w4.z + f0.w * w4.w;
            a1 += f1.x * w4.x + f1.y * w4.y + f1.z * w4.z + f1.w * w4.w;
        }
        sv[gp * 2][ch]     = gelu_exact(a0);
        sv[gp * 2 + 1][ch] = gelu_exact(a1);
    }
    __syncthreads();

    for (int idx = tid; idx < 256 + 640; idx += 256) {
        if (idx < 256) {
            int g = idx >> 6, ch = idx & 63;
            float a = c1b[ch];
            const float* wr = c1W + (size_t)ch * 128;
            for (int k = 0; k < 128; ++k) a += sv[g][k] * wr[k];
            t64[g][ch] = gelu_exact(a);
        } else {
            int j = idx - 256;
            int g = j / 160, r = j - g * 160;
            int e = r >> 5, hh = r & 31;
            float a = ad1b[e * 32 + hh];
            const float* wr = ad1W + (size_t)(e * 32 + hh) * 128;
            for (int k = 0; k < 128; ++k) a += sv[g][k] * wr[k];
            h1s[g][e][hh] = gelu_exact(a);
        }
    }
    if (tid < 128) {
        int g = tid >> 5, r = tid & 31;
        float a = 0.f;
#pragma unroll
        for (int k = 0; k < 4; ++k) a += sv[g][r * 4 + k] * binW[r * 4 + k];
        binred[g][r] = a;
    }
    __syncthreads();

    if (tid < 24) {            // cls: 6 x 4 graphs
        int g = tid / 6, c = tid - g * 6;
        float a = c2b[c];
        const float* wr = c2W + (size_t)c * 64;
        for (int k = 0; k < 64; ++k) a += t64[g][k] * wr[k];
        out[4800 + (size_t)(b0 + g) * 6 + c] = a;
    }
    if (tid >= 32 && tid < 52) {  // per: 5 x 4 graphs
        int j = tid - 32;
        int g = j / 5, e = j - g * 5;
        float a = ad2b[e];
        const float* wr = ad2W + (size_t)e * 32;
        for (int k = 0; k < 32; ++k) a += h1s[g][e][k] * wr[k];
        out[800 + (size_t)e * 800 + (b0 + g)] = a;
    }
    if (tid >= 64 && tid < 68) {  // binary: 4 graphs
        int g = tid - 64;
        float a = binB[0];
        for (int r = 0; r < 32; ++r) a += binred[g][r];
        out[b0 + g] = a;
    }
}

extern "C" void kernel_launch(void* const* d_in, const int* in_sizes, int n_in,
                              void* d_out, int out_size, void* d_ws, size_t ws_size,
                              hipStream_t stream) {
    const float* x       = (const float*)d_in[0];
    const int*   ei      = (const int*)d_in[1];
    const int*   batch   = (const int*)d_in[2];
    const float* rnafm   = (const float*)d_in[3];
    const float* hand    = (const float*)d_in[4];
    const float* gW[3]  = {(const float*)d_in[5],  (const float*)d_in[9],  (const float*)d_in[13]};
    const float* gAs[3] = {(const float*)d_in[6],  (const float*)d_in[10], (const float*)d_in[14]};
    const float* gAd[3] = {(const float*)d_in[7],  (const float*)d_in[11], (const float*)d_in[15]};
    const float* gB[3]  = {(const float*)d_in[8],  (const float*)d_in[12], (const float*)d_in[16]};
    const float* poolW = (const float*)d_in[17];
    const float* poolB = (const float*)d_in[18];
    const float* e1W = (const float*)d_in[19]; const float* e1b = (const float*)d_in[20];
    const float* lng = (const float*)d_in[21]; const float* lnb = (const float*)d_in[22];
    const float* e2W = (const float*)d_in[23]; const float* e2b = (const float*)d_in[24];
    const float* binW = (const float*)d_in[25]; const float* binB = (const float*)d_in[26];
    const float* ad1W = (const float*)d_in[27]; const float* ad1b = (const float*)d_in[28];
    const float* ad2W = (const float*)d_in[29]; const float* ad2b = (const float*)d_in[30];
    const float* c1W = (const float*)d_in[31]; const float* c1b = (const float*)d_in[32];
    const float* c2W = (const float*)d_in[33]; const float* c2b = (const float*)d_in[34];
    float* out = (float*)d_out;

    float* ws = (float*)d_ws;
    size_t off = 0;
    unsigned char* hfull = (unsigned char*)(ws + off); off += (size_t)N_NODES * 64; // fp8 [N,256]
    float* xcur   = ws + off; off += (size_t)N_NODES * 64;
    float* sArr   = ws + off; off += (size_t)N_NODES * 4;
    float* dArr   = ws + off; off += (size_t)N_NODES * 4;
    int*   cnt    = (int*)(ws + off); off += N_NODES;
    int*   csrc   = (int*)(ws + off); off += (size_t)N_NODES * PADDEG;
    float* logit  = ws + off; off += N_NODES;
    float* pmax   = ws + off; off += NPMAX;
    float* pooled = ws + off; off += (size_t)N_B * 64;
    float* part   = ws + off; off += (size_t)2 * N_B * 256;
    int*   start  = (int*)(ws + off); off += (N_B + 1);
    float* gsum   = ws + off; off += 1;

    // ---- one-time per call: padded CSR + segment bounds + gsum=0 (fused) ----
    hipMemsetAsync(cnt, 0, N_NODES * sizeof(int), stream);
    setup_csr<<<(N_EDGES + 255) / 256, 256, 0, stream>>>(ei, batch, cnt, csrc, start, gsum);

    // ---- 3 GAT layers ----
    for (int layer = 0; layer < 3; ++layer) {
        const float* xin = (layer == 0) ? x : xcur;
        if (layer == 0)
            gat_transform<21><<<512, 256, 0, stream>>>(xin, gW[0], gAs[0], gAd[0], hfull, sArr, dArr);
        else
            gat_transform<64><<<512, 256, 0, stream>>>(xin, gW[layer], gAs[layer], gAd[layer], hfull, sArr, dArr);
        if (layer < 2)
            gat_gather<false><<<N_NODES / 16, 256, 0, stream>>>(cnt, csrc, sArr, dArr, hfull,
                                                                gB[layer], nullptr, nullptr,
                                                                xcur, nullptr, nullptr);
        else
            gat_gather<true><<<N_NODES / 16, 256, 0, stream>>>(cnt, csrc, sArr, dArr, hfull,
                                                               gB[2], poolW, poolB,
                                                               xcur, logit, pmax);
    }

    // ---- pooling + heads ----
    pool_graph<<<N_B, 256, 0, stream>>>(xcur, logit, pmax, start, pooled, gsum);

    head1_part<<<(N_B / GB1) * 2, 256, 0, stream>>>(pooled, gsum, rnafm, hand, e1W, part);
    head_fused<<<N_B / 4, 256, 0, stream>>>(part, e1b, lng, lnb, e2W, e2b,
                                            binW, binB, ad1W, ad1b, ad2W, ad2b,
                                            c1W, c1b, c2W, c2b, out);
}